// Round 13
// baseline (411.452 us; speedup 1.0000x reference)
//
#include <hip/hip_runtime.h>

#define BN 16384
#define DD 16
#define KNN 25
#define QB 16
#define CAPG 256
#define NSQ 4

typedef unsigned long long u64;
typedef __attribute__((ext_vector_type(8))) short bf16x8;
typedef __attribute__((ext_vector_type(4))) float f32x4;

__device__ __forceinline__ u64 wave_min_u64(u64 v) {
#pragma unroll
    for (int off = 32; off >= 1; off >>= 1) {
        unsigned lo = (unsigned)v, hi = (unsigned)(v >> 32);
        unsigned olo = __shfl_xor(lo, off, 64);
        unsigned ohi = __shfl_xor(hi, off, 64);
        u64 o = (((u64)ohi) << 32) | olo;
        if (o < v) v = o;
    }
    return v;
}

__device__ __forceinline__ unsigned short f2bf(float f) {
    unsigned u = __float_as_uint(f);
    unsigned r = (u + 0x7FFFu + ((u >> 16) & 1u)) >> 16;   // RNE
    return (unsigned short)r;
}

// ---------------- prep: norms + split-precision bf16 [hi(16)|lo(16)] ----------------
__global__ void prep_kernel(const float* __restrict__ raw, uint4* __restrict__ rawhl,
                            float* __restrict__ nrm) {
    int j = blockIdx.x * 256 + threadIdx.x;
    if (j >= BN) return;
    const float4* rv = (const float4*)raw + j * 4;
    float4 a = rv[0], b = rv[1], c = rv[2], d = rv[3];
    float x[16] = {a.x,a.y,a.z,a.w,b.x,b.y,b.z,b.w,c.x,c.y,c.z,c.w,d.x,d.y,d.z,d.w};
    float s = 0.f;
#pragma unroll
    for (int i = 0; i < 16; ++i) s = fmaf(x[i], x[i], s);
    nrm[j] = s;
    unsigned hp[8], lp[8];
#pragma unroll
    for (int i = 0; i < 8; ++i) {
        unsigned short h0 = f2bf(x[2*i]), h1 = f2bf(x[2*i+1]);
        float f0 = __uint_as_float(((unsigned)h0) << 16);
        float f1 = __uint_as_float(((unsigned)h1) << 16);
        unsigned short l0 = f2bf(x[2*i] - f0), l1 = f2bf(x[2*i+1] - f1);
        hp[i] = (unsigned)h0 | ((unsigned)h1 << 16);
        lp[i] = (unsigned)l0 | ((unsigned)l1 << 16);
    }
    uint4* dst = rawhl + j * 4;
    dst[0] = make_uint4(hp[0], hp[1], hp[2], hp[3]);
    dst[1] = make_uint4(hp[4], hp[5], hp[6], hp[7]);
    dst[2] = make_uint4(lp[0], lp[1], lp[2], lp[3]);
    dst[3] = make_uint4(lp[4], lp[5], lp[6], lp[7]);
}

// ---------------- recon partials ----------------
__global__ void recon_kernel(const float* __restrict__ o, const float* __restrict__ t,
                             float* __restrict__ part) {
    __shared__ float red[256];
    int tid = threadIdx.x;
    int idx = blockIdx.x * 256 + tid;
    float s = 0.f;
    for (int i = idx; i < BN * DD; i += 256 * 256) {
        float d = o[i] - t[i];
        s = fmaf(d, d, s);
    }
    red[tid] = s;
    __syncthreads();
    for (int off = 128; off > 0; off >>= 1) {
        if (tid < off) red[tid] += red[tid + off];
        __syncthreads();
    }
    if (tid == 0) part[blockIdx.x] = red[0];
}

// ------------- knnb: 16 rows x half-point-range per block, collect to global -------------
__global__ __launch_bounds__(256, 8) void knnb_kernel(const uint4* __restrict__ rawhl,
                                                      const float* __restrict__ nrm,
                                                      unsigned* __restrict__ gcnt,
                                                      u64* __restrict__ glist) {
    const int tid  = threadIdx.x;
    const int lane = tid & 63;
    const int w    = tid >> 6;
    const int l15  = lane & 15;
    const int g    = lane >> 4;
    const int qg   = blockIdx.x >> 1;
    const int h    = blockIdx.x & 1;
    const int row0 = qg * QB;
    const int pbase = h * (BN / 2);

    __shared__ float minbuf[QB][64];   // 4 KB
    __shared__ float Bv[QB];

    const bf16x8* rb = (const bf16x8*)rawhl;

    // A-fragments: A[row=l15][k=8g..]; A1=[q_hi|q_hi], A2=[q_lo|q_lo]
    bf16x8 A1 = rb[(row0 + l15) * 4 + (g & 1)];
    bf16x8 A2 = rb[(row0 + l15) * 4 + 2 + (g & 1)];
    float4 vqn = *(const float4*)(nrm + row0 + g * 4);

    const float INFf = __builtin_inff();

    // ---- phase A: bound from 4096-pt subset of this half ----
    float mn0 = INFf, mn1 = INFf, mn2 = INFf, mn3 = INFf;
    for (int t = w; t < 256; t += 4) {
        int pt = pbase + t * 16 + l15;
        bf16x8 Bf = rb[pt * 4 + g];
        float pn = nrm[pt];
        f32x4 c = {0.f, 0.f, 0.f, 0.f};
        c = __builtin_amdgcn_mfma_f32_16x16x32_bf16(A1, Bf, c, 0, 0, 0);
        c = __builtin_amdgcn_mfma_f32_16x16x32_bf16(A2, Bf, c, 0, 0, 0);
        mn0 = fminf(mn0, fmaxf(fmaf(-2.f, c[0], vqn.x + pn), 0.f));
        mn1 = fminf(mn1, fmaxf(fmaf(-2.f, c[1], vqn.y + pn), 0.f));
        mn2 = fminf(mn2, fmaxf(fmaf(-2.f, c[2], vqn.z + pn), 0.f));
        mn3 = fminf(mn3, fmaxf(fmaf(-2.f, c[3], vqn.w + pn), 0.f));
    }
    minbuf[g * 4 + 0][w * 16 + l15] = mn0;
    minbuf[g * 4 + 1][w * 16 + l15] = mn1;
    minbuf[g * 4 + 2][w * 16 + l15] = mn2;
    minbuf[g * 4 + 3][w * 16 + l15] = mn3;
    __syncthreads();

    // ---- bound: 26 value-extractions over the 64 trackers; wave w rows 4w..4w+3 ----
    for (int rr = 0; rr < 4; ++rr) {
        int row = 4 * w + rr;
        float v = minbuf[row][lane];
        float bk = INFf;
        for (int it = 0; it < KNN + 1; ++it) {
            float m = v;
#pragma unroll
            for (int off = 32; off >= 1; off >>= 1)
                m = fminf(m, __shfl_xor(m, off, 64));
            bk = m;
            if (v == m) v = INFf;
        }
        if (lane == 0) Bv[row] = bk;
    }
    __syncthreads();

    float4 vb;
    vb.x = Bv[g * 4 + 0]; vb.y = Bv[g * 4 + 1];
    vb.z = Bv[g * 4 + 2]; vb.w = Bv[g * 4 + 3];

    // ---- phase B: scan this half (8192 pts), collect d2 <= bound to GLOBAL ----
    for (int t = w; t < 512; t += 4) {
        int pt = pbase + t * 16 + l15;
        bf16x8 Bf = rb[pt * 4 + g];
        float pn = nrm[pt];
        f32x4 c = {0.f, 0.f, 0.f, 0.f};
        c = __builtin_amdgcn_mfma_f32_16x16x32_bf16(A1, Bf, c, 0, 0, 0);
        c = __builtin_amdgcn_mfma_f32_16x16x32_bf16(A2, Bf, c, 0, 0, 0);
#define COLL(r, QN, BB) { \
        float d2 = fmaxf(fmaf(-2.f, c[r], QN + pn), 0.f); \
        if (d2 <= BB) { \
            int q = row0 + g * 4 + r; \
            unsigned pos = atomicAdd(&gcnt[q], 1u); \
            if (pos < CAPG) \
                glist[(u64)q * CAPG + pos] = \
                    (((u64)__float_as_uint(d2)) << 32) | (unsigned)pt; } }
        COLL(0, vqn.x, vb.x) COLL(1, vqn.y, vb.y)
        COLL(2, vqn.z, vb.z) COLL(3, vqn.w, vb.w)
#undef COLL
    }
}

// ------------- sel_eigen: 1 row per wave; select top-25 then eigen solve -------------
__global__ __launch_bounds__(256, 7) void sel_eigen_kernel(const float* __restrict__ latent,
                                                           const float* __restrict__ raw,
                                                           const unsigned* __restrict__ gcnt,
                                                           const u64* __restrict__ glist,
                                                           float* __restrict__ tsa) {
    const int tid  = threadIdx.x;
    const int lane = tid & 63;
    const int w    = tid >> 6;
    const int l15  = lane & 15;
    const int g    = lane >> 4;
    const int qi   = blockIdx.x * 4 + w;

    __shared__ float smem[4 * 1280];   // 20.5 KB, wave-private slices
    float* ews  = smem + w * 1280;
    float* pts  = ews;          // 25 x stride 20
    float* Arow = ews + 512;
    float* Acol = ews + 832;
    float* vbuf = ews + 1152;   // 16
    float* ubuf = ews + 1168;   // 32
    int*   nbrw = (int*)(ews + 1200); // 25

    const float INFf = __builtin_inff();

    // ---- selection: register-resident 26 extract-mins (iter 0 = self) ----
    {
        int cnt = (int)gcnt[qi]; if (cnt > CAPG) cnt = CAPG;
        const u64* L = glist + (u64)qi * CAPG;
        u64 k0 = (lane < cnt)       ? L[lane]       : ~0ull;
        u64 k1 = (lane + 64 < cnt)  ? L[lane + 64]  : ~0ull;
        u64 k2 = (lane + 128 < cnt) ? L[lane + 128] : ~0ull;
        u64 k3 = (lane + 192 < cnt) ? L[lane + 192] : ~0ull;
        for (int it = 0; it < KNN + 1; ++it) {
            u64 best = k0;
            if (k1 < best) best = k1;
            if (k2 < best) best = k2;
            if (k3 < best) best = k3;
            best = wave_min_u64(best);
            if (k0 == best) k0 = ~0ull;
            if (k1 == best) k1 = ~0ull;
            if (k2 == best) k2 = ~0ull;
            if (k3 == best) k3 = ~0ull;
            if (lane == 0 && it > 0) nbrw[it - 1] = (int)(best & 0xffffffffu);
        }
    }

    const int q4 = g << 2;
    const int jc = l15;

    for (int m = 0; m < 2; ++m) {
        const float4* src4 = (const float4*)((m == 0) ? latent : raw);
        if (lane < KNN) {
            int nb = nbrw[lane];
            float4 r0 = src4[nb * 4 + 0], r1 = src4[nb * 4 + 1];
            float4 r2 = src4[nb * 4 + 2], r3 = src4[nb * 4 + 3];
            float4* dst = (float4*)(pts + lane * 20);
            dst[0] = r0; dst[1] = r1; dst[2] = r2; dst[3] = r3;
        }
        // gram + mean adjustment: C = G - s s^T / 25
        float g0 = 0, g1 = 0, g2 = 0, g3 = 0;
        float s0 = 0, s1 = 0, s2 = 0, s3 = 0, sj = 0;
        for (int k = 0; k < KNN; ++k) {
            float4 qv = *(const float4*)(pts + k * 20 + q4);
            float rj = pts[k * 20 + jc];
            g0 = fmaf(qv.x, rj, g0); g1 = fmaf(qv.y, rj, g1);
            g2 = fmaf(qv.z, rj, g2); g3 = fmaf(qv.w, rj, g3);
            s0 += qv.x; s1 += qv.y; s2 += qv.z; s3 += qv.w; sj += rj;
        }
        const float i25 = 1.0f / 25.0f;
        float sjs = sj * i25;
        float a0 = fmaf(-s0, sjs, g0);
        float a1 = fmaf(-s1, sjs, g1);
        float a2 = fmaf(-s2, sjs, g2);
        float a3 = fmaf(-s3, sjs, g3);

        for (int sq = 0; sq < NSQ; ++sq) {
            Arow[(q4 + 0) * 20 + jc] = a0;
            Arow[(q4 + 1) * 20 + jc] = a1;
            Arow[(q4 + 2) * 20 + jc] = a2;
            Arow[(q4 + 3) * 20 + jc] = a3;
            *(float4*)(Acol + jc * 20 + q4) = make_float4(a0, a1, a2, a3);
            float t = 0.f;
            if (jc == q4 + 0) t += a0;
            if (jc == q4 + 1) t += a1;
            if (jc == q4 + 2) t += a2;
            if (jc == q4 + 3) t += a3;
#pragma unroll
            for (int off = 32; off >= 1; off >>= 1) t += __shfl_xor(t, off, 64);
            float itr = (t > 0.f) ? (1.0f / t) : 1.0f;
            float b0_ = 0, b1_ = 0, b2_ = 0, b3_ = 0;
#pragma unroll
            for (int k = 0; k < DD; ++k) {
                float4 ck = *(const float4*)(Acol + k * 20 + q4);
                float rk = Arow[k * 20 + jc];
                b0_ = fmaf(ck.x, rk, b0_);
                b1_ = fmaf(ck.y, rk, b1_);
                b2_ = fmaf(ck.z, rk, b2_);
                b3_ = fmaf(ck.w, rk, b3_);
            }
            float sc = itr * itr;
            a0 = b0_ * sc; a1 = b1_ * sc; a2 = b2_ * sc; a3 = b3_ * sc;
        }

        // column norms + argmax (tie: lower j)
        float cn = a0 * a0;
        cn = fmaf(a1, a1, cn); cn = fmaf(a2, a2, cn); cn = fmaf(a3, a3, cn);
        cn += __shfl_xor(cn, 16, 64);
        cn += __shfl_xor(cn, 32, 64);
        int bj = jc;
#pragma unroll
        for (int off = 32; off >= 1; off >>= 1) {
            float on = __shfl_xor(cn, off, 64);
            int   oj = __shfl_xor(bj, off, 64);
            if (on > cn || (on == cn && oj < bj)) { cn = on; bj = oj; }
        }

        if (jc == bj) {
            vbuf[q4 + 0] = a0; vbuf[q4 + 1] = a1;
            vbuf[q4 + 2] = a2; vbuf[q4 + 3] = a3;
        }
        float vj = vbuf[jc];
        float w0 = a0 * vj, w1 = a1 * vj, w2 = a2 * vj, w3 = a3 * vj;
#pragma unroll
        for (int off = 1; off < 16; off <<= 1) {
            w0 += __shfl_xor(w0, off, 64);
            w1 += __shfl_xor(w1, off, 64);
            w2 += __shfl_xor(w2, off, 64);
            w3 += __shfl_xor(w3, off, 64);
        }
        if (jc == 0) {
            vbuf[q4 + 0] = w0; vbuf[q4 + 1] = w1;
            vbuf[q4 + 2] = w2; vbuf[q4 + 3] = w3;
        }
        vj = vbuf[jc];
        float x0 = a0 * vj, x1 = a1 * vj, x2 = a2 * vj, x3 = a3 * vj;
#pragma unroll
        for (int off = 1; off < 16; off <<= 1) {
            x0 += __shfl_xor(x0, off, 64);
            x1 += __shfl_xor(x1, off, 64);
            x2 += __shfl_xor(x2, off, 64);
            x3 += __shfl_xor(x3, off, 64);
        }
        float nv = x0 * x0;
        nv = fmaf(x1, x1, nv); nv = fmaf(x2, x2, nv); nv = fmaf(x3, x3, nv);
        nv += __shfl_xor(nv, 16, 64);
        nv += __shfl_xor(nv, 32, 64);
        float inv = rsqrtf(fmaxf(nv, 1e-30f));
        if (jc == 0) {
            ubuf[m * 16 + q4 + 0] = x0 * inv;
            ubuf[m * 16 + q4 + 1] = x1 * inv;
            ubuf[m * 16 + q4 + 2] = x2 * inv;
            ubuf[m * 16 + q4 + 3] = x3 * inv;
        }
    }
    float du = ubuf[jc] * ubuf[16 + jc];
#pragma unroll
    for (int off = 1; off < 16; off <<= 1) du += __shfl_xor(du, off, 64);
    if (lane == 0) tsa[qi] = 2.0f - 2.0f * du * du;
}

// ---------------- finalize ----------------
__global__ void finalize_kernel(const float* __restrict__ tsa,
                                const float* __restrict__ part,
                                float* __restrict__ out) {
    __shared__ float red[256];
    int tid = threadIdx.x;
    float s = 0.f;
    for (int i = tid; i < BN; i += 256) s += tsa[i];
    red[tid] = s;
    __syncthreads();
    for (int off = 128; off > 0; off >>= 1) {
        if (tid < off) red[tid] += red[tid + off];
        __syncthreads();
    }
    float tsaSum = red[0];
    __syncthreads();
    red[tid] = part[tid];
    __syncthreads();
    for (int off = 128; off > 0; off >>= 1) {
        if (tid < off) red[tid] += red[tid + off];
        __syncthreads();
    }
    if (tid == 0)
        out[0] = red[0] * (1.0f / (float)(BN * DD)) + 0.1f * (tsaSum * (1.0f / (float)BN));
}

extern "C" void kernel_launch(void* const* d_in, const int* in_sizes, int n_in,
                              void* d_out, int out_size, void* d_ws, size_t ws_size,
                              hipStream_t stream) {
    const float* outputs = (const float*)d_in[0];
    const float* targets = (const float*)d_in[1];
    const float* latent  = (const float*)d_in[2];
    const float* raw     = (const float*)d_in[3];

    char* base = (char*)d_ws;
    float*    tsa   = (float*)base;                               // BN f32
    float*    part  = (float*)(base + BN * 4);                    // 256 f32
    float*    nrm   = (float*)(base + BN * 4 + 1024);             // BN f32
    uint4*    rawhl = (uint4*)(base + 2 * BN * 4 + 1024);         // BN*64 B
    unsigned* gcnt  = (unsigned*)(base + 2 * BN * 4 + 1024 + BN * 64);       // BN u32
    u64*      glist = (u64*)(base + 3 * BN * 4 + 1024 + BN * 64);            // BN*CAPG u64

    prep_kernel<<<BN / 256, 256, 0, stream>>>(raw, rawhl, nrm);
    recon_kernel<<<256, 256, 0, stream>>>(outputs, targets, part);
    hipMemsetAsync(gcnt, 0, BN * sizeof(unsigned), stream);
    knnb_kernel<<<2 * (BN / QB), 256, 0, stream>>>(rawhl, nrm, gcnt, glist);
    sel_eigen_kernel<<<BN / 4, 256, 0, stream>>>(latent, raw, gcnt, glist, tsa);
    finalize_kernel<<<1, 256, 0, stream>>>(tsa, part, (float*)d_out);
}

// Round 14
// 325.153 us; speedup vs baseline: 1.2654x; 1.2654x over previous
//
#include <hip/hip_runtime.h>

#define BN 16384
#define DD 16
#define KNN 25
#define QB 16
#define CAPH 128
#define NSQ 4

typedef unsigned long long u64;
typedef __attribute__((ext_vector_type(8))) short bf16x8;
typedef __attribute__((ext_vector_type(4))) float f32x4;

__device__ __forceinline__ u64 wave_min_u64(u64 v) {
#pragma unroll
    for (int off = 32; off >= 1; off >>= 1) {
        unsigned lo = (unsigned)v, hi = (unsigned)(v >> 32);
        unsigned olo = __shfl_xor(lo, off, 64);
        unsigned ohi = __shfl_xor(hi, off, 64);
        u64 o = (((u64)ohi) << 32) | olo;
        if (o < v) v = o;
    }
    return v;
}

__device__ __forceinline__ unsigned short f2bf(float f) {
    unsigned u = __float_as_uint(f);
    unsigned r = (u + 0x7FFFu + ((u >> 16) & 1u)) >> 16;   // RNE
    return (unsigned short)r;
}

// ---------------- prep: norms + split-precision bf16 [hi(16)|lo(16)] ----------------
__global__ void prep_kernel(const float* __restrict__ raw, uint4* __restrict__ rawhl,
                            float* __restrict__ nrm) {
    int j = blockIdx.x * 256 + threadIdx.x;
    if (j >= BN) return;
    const float4* rv = (const float4*)raw + j * 4;
    float4 a = rv[0], b = rv[1], c = rv[2], d = rv[3];
    float x[16] = {a.x,a.y,a.z,a.w,b.x,b.y,b.z,b.w,c.x,c.y,c.z,c.w,d.x,d.y,d.z,d.w};
    float s = 0.f;
#pragma unroll
    for (int i = 0; i < 16; ++i) s = fmaf(x[i], x[i], s);
    nrm[j] = s;
    unsigned hp[8], lp[8];
#pragma unroll
    for (int i = 0; i < 8; ++i) {
        unsigned short h0 = f2bf(x[2*i]), h1 = f2bf(x[2*i+1]);
        float f0 = __uint_as_float(((unsigned)h0) << 16);
        float f1 = __uint_as_float(((unsigned)h1) << 16);
        unsigned short l0 = f2bf(x[2*i] - f0), l1 = f2bf(x[2*i+1] - f1);
        hp[i] = (unsigned)h0 | ((unsigned)h1 << 16);
        lp[i] = (unsigned)l0 | ((unsigned)l1 << 16);
    }
    uint4* dst = rawhl + j * 4;
    dst[0] = make_uint4(hp[0], hp[1], hp[2], hp[3]);
    dst[1] = make_uint4(hp[4], hp[5], hp[6], hp[7]);
    dst[2] = make_uint4(lp[0], lp[1], lp[2], lp[3]);
    dst[3] = make_uint4(lp[4], lp[5], lp[6], lp[7]);
}

// ---------------- recon partials ----------------
__global__ void recon_kernel(const float* __restrict__ o, const float* __restrict__ t,
                             float* __restrict__ part) {
    __shared__ float red[256];
    int tid = threadIdx.x;
    int idx = blockIdx.x * 256 + tid;
    float s = 0.f;
    for (int i = idx; i < BN * DD; i += 256 * 256) {
        float d = o[i] - t[i];
        s = fmaf(d, d, s);
    }
    red[tid] = s;
    __syncthreads();
    for (int off = 128; off > 0; off >>= 1) {
        if (tid < off) red[tid] += red[tid + off];
        __syncthreads();
    }
    if (tid == 0) part[blockIdx.x] = red[0];
}

// ------- knnb: 16 rows x half-point-range; LDS collect, coalesced global flush -------
__global__ __launch_bounds__(256, 8) void knnb_kernel(const uint4* __restrict__ rawhl,
                                                      const float* __restrict__ nrm,
                                                      unsigned* __restrict__ gcnt2,
                                                      u64* __restrict__ glist) {
    const int tid  = threadIdx.x;
    const int lane = tid & 63;
    const int w    = tid >> 6;
    const int l15  = lane & 15;
    const int g    = lane >> 4;
    const int qg   = blockIdx.x >> 1;
    const int h    = blockIdx.x & 1;
    const int row0 = qg * QB;
    const int pbase = h * (BN / 2);

    // 16 KB overlay: phase A = minbuf[16][64] f32, phase B = lists[16][CAPH] u64
    __shared__ __align__(16) char smem[QB * CAPH * 8];
    u64   (*lists)[CAPH] = (u64 (*)[CAPH])smem;
    float (*minbuf)[64]  = (float (*)[64])smem;
    __shared__ int   lcnt[QB];
    __shared__ float Bv[QB];

    if (tid < QB) lcnt[tid] = 0;

    const bf16x8* rb = (const bf16x8*)rawhl;

    // A-fragments: A[row=l15][k=8g..]; A1=[q_hi|q_hi], A2=[q_lo|q_lo]
    bf16x8 A1 = rb[(row0 + l15) * 4 + (g & 1)];
    bf16x8 A2 = rb[(row0 + l15) * 4 + 2 + (g & 1)];
    float4 vqn = *(const float4*)(nrm + row0 + g * 4);

    const float INFf = __builtin_inff();

    // ---- phase A: bound from 4096-pt subset of this half ----
    float mn0 = INFf, mn1 = INFf, mn2 = INFf, mn3 = INFf;
    for (int t = w; t < 256; t += 4) {
        int pt = pbase + t * 16 + l15;
        bf16x8 Bf = rb[pt * 4 + g];
        float pn = nrm[pt];
        f32x4 c = {0.f, 0.f, 0.f, 0.f};
        c = __builtin_amdgcn_mfma_f32_16x16x32_bf16(A1, Bf, c, 0, 0, 0);
        c = __builtin_amdgcn_mfma_f32_16x16x32_bf16(A2, Bf, c, 0, 0, 0);
        mn0 = fminf(mn0, fmaxf(fmaf(-2.f, c[0], vqn.x + pn), 0.f));
        mn1 = fminf(mn1, fmaxf(fmaf(-2.f, c[1], vqn.y + pn), 0.f));
        mn2 = fminf(mn2, fmaxf(fmaf(-2.f, c[2], vqn.z + pn), 0.f));
        mn3 = fminf(mn3, fmaxf(fmaf(-2.f, c[3], vqn.w + pn), 0.f));
    }
    minbuf[g * 4 + 0][w * 16 + l15] = mn0;
    minbuf[g * 4 + 1][w * 16 + l15] = mn1;
    minbuf[g * 4 + 2][w * 16 + l15] = mn2;
    minbuf[g * 4 + 3][w * 16 + l15] = mn3;
    __syncthreads();

    // ---- bound: 26 value-extractions over 64 trackers; wave w rows 4w..4w+3 ----
    for (int rr = 0; rr < 4; ++rr) {
        int row = 4 * w + rr;
        float v = minbuf[row][lane];
        float bk = INFf;
        for (int it = 0; it < KNN + 1; ++it) {
            float m = v;
#pragma unroll
            for (int off = 32; off >= 1; off >>= 1)
                m = fminf(m, __shfl_xor(m, off, 64));
            bk = m;
            if (v == m) v = INFf;
        }
        if (lane == 0) Bv[row] = bk;
    }
    __syncthreads();   // minbuf dead; lists overlay begins

    float4 vb;
    vb.x = Bv[g * 4 + 0]; vb.y = Bv[g * 4 + 1];
    vb.z = Bv[g * 4 + 2]; vb.w = Bv[g * 4 + 3];

    // ---- phase B: scan this half (8192 pts), collect d2 <= bound into LDS ----
    for (int t = w; t < 512; t += 4) {
        int pt = pbase + t * 16 + l15;
        bf16x8 Bf = rb[pt * 4 + g];
        float pn = nrm[pt];
        f32x4 c = {0.f, 0.f, 0.f, 0.f};
        c = __builtin_amdgcn_mfma_f32_16x16x32_bf16(A1, Bf, c, 0, 0, 0);
        c = __builtin_amdgcn_mfma_f32_16x16x32_bf16(A2, Bf, c, 0, 0, 0);
#define COLL(r, QN, BB) { \
        float d2 = fmaxf(fmaf(-2.f, c[r], QN + pn), 0.f); \
        if (d2 <= BB) { \
            int q = g * 4 + r; \
            int pos = atomicAdd(&lcnt[q], 1); \
            if (pos < CAPH) \
                lists[q][pos] = (((u64)__float_as_uint(d2)) << 32) | (unsigned)pt; } }
        COLL(0, vqn.x, vb.x) COLL(1, vqn.y, vb.y)
        COLL(2, vqn.z, vb.z) COLL(3, vqn.w, vb.w)
#undef COLL
    }
    __syncthreads();

    // ---- flush: coalesced bulk writes, one count store per query-half ----
    for (int rr = 0; rr < 4; ++rr) {
        int qi = 4 * w + rr;
        int cnt = lcnt[qi]; if (cnt > CAPH) cnt = CAPH;
        u64* dst = glist + ((u64)(row0 + qi) * 2 + h) * CAPH;
        for (int e = lane; e < cnt; e += 64) dst[e] = lists[qi][e];
        if (lane == 0) gcnt2[(row0 + qi) * 2 + h] = (unsigned)cnt;
    }
}

// ------------- sel_eigen: 1 row per wave; merge halves, top-25, eigen solve -------------
__global__ __launch_bounds__(256, 7) void sel_eigen_kernel(const float* __restrict__ latent,
                                                           const float* __restrict__ raw,
                                                           const unsigned* __restrict__ gcnt2,
                                                           const u64* __restrict__ glist,
                                                           float* __restrict__ tsa) {
    const int tid  = threadIdx.x;
    const int lane = tid & 63;
    const int w    = tid >> 6;
    const int l15  = lane & 15;
    const int g    = lane >> 4;
    const int qi   = blockIdx.x * 4 + w;

    __shared__ float smem[4 * 1280];   // 20.5 KB, wave-private slices
    float* ews  = smem + w * 1280;
    float* pts  = ews;          // 25 x stride 20
    float* Arow = ews + 512;
    float* Acol = ews + 832;
    float* vbuf = ews + 1152;   // 16
    float* ubuf = ews + 1168;   // 32
    int*   nbrw = (int*)(ews + 1200); // 25

    // ---- selection: merge 2 half-lists, register 26 extract-mins (iter 0 = self) ----
    {
        int c0 = (int)gcnt2[qi * 2 + 0]; if (c0 > CAPH) c0 = CAPH;
        int c1 = (int)gcnt2[qi * 2 + 1]; if (c1 > CAPH) c1 = CAPH;
        const u64* L = glist + (u64)qi * 2 * CAPH;
        u64 k0, k1, k2, k3;
#define GET(dst, i) { int ii = (i); \
        if (ii < c0) dst = L[ii]; \
        else { int jj = ii - c0; dst = (jj < c1) ? L[CAPH + jj] : ~0ull; } }
        GET(k0, lane) GET(k1, lane + 64) GET(k2, lane + 128) GET(k3, lane + 192)
#undef GET
        for (int it = 0; it < KNN + 1; ++it) {
            u64 best = k0;
            if (k1 < best) best = k1;
            if (k2 < best) best = k2;
            if (k3 < best) best = k3;
            best = wave_min_u64(best);
            if (k0 == best) k0 = ~0ull;
            if (k1 == best) k1 = ~0ull;
            if (k2 == best) k2 = ~0ull;
            if (k3 == best) k3 = ~0ull;
            if (lane == 0 && it > 0) nbrw[it - 1] = (int)(best & 0xffffffffu);
        }
    }

    const int q4 = g << 2;
    const int jc = l15;

    for (int m = 0; m < 2; ++m) {
        const float4* src4 = (const float4*)((m == 0) ? latent : raw);
        if (lane < KNN) {
            int nb = nbrw[lane];
            float4 r0 = src4[nb * 4 + 0], r1 = src4[nb * 4 + 1];
            float4 r2 = src4[nb * 4 + 2], r3 = src4[nb * 4 + 3];
            float4* dst = (float4*)(pts + lane * 20);
            dst[0] = r0; dst[1] = r1; dst[2] = r2; dst[3] = r3;
        }
        // gram + mean adjustment: C = G - s s^T / 25
        float g0 = 0, g1 = 0, g2 = 0, g3 = 0;
        float s0 = 0, s1 = 0, s2 = 0, s3 = 0, sj = 0;
        for (int k = 0; k < KNN; ++k) {
            float4 qv = *(const float4*)(pts + k * 20 + q4);
            float rj = pts[k * 20 + jc];
            g0 = fmaf(qv.x, rj, g0); g1 = fmaf(qv.y, rj, g1);
            g2 = fmaf(qv.z, rj, g2); g3 = fmaf(qv.w, rj, g3);
            s0 += qv.x; s1 += qv.y; s2 += qv.z; s3 += qv.w; sj += rj;
        }
        const float i25 = 1.0f / 25.0f;
        float sjs = sj * i25;
        float a0 = fmaf(-s0, sjs, g0);
        float a1 = fmaf(-s1, sjs, g1);
        float a2 = fmaf(-s2, sjs, g2);
        float a3 = fmaf(-s3, sjs, g3);

        for (int sq = 0; sq < NSQ; ++sq) {
            Arow[(q4 + 0) * 20 + jc] = a0;
            Arow[(q4 + 1) * 20 + jc] = a1;
            Arow[(q4 + 2) * 20 + jc] = a2;
            Arow[(q4 + 3) * 20 + jc] = a3;
            *(float4*)(Acol + jc * 20 + q4) = make_float4(a0, a1, a2, a3);
            float t = 0.f;
            if (jc == q4 + 0) t += a0;
            if (jc == q4 + 1) t += a1;
            if (jc == q4 + 2) t += a2;
            if (jc == q4 + 3) t += a3;
#pragma unroll
            for (int off = 32; off >= 1; off >>= 1) t += __shfl_xor(t, off, 64);
            float itr = (t > 0.f) ? (1.0f / t) : 1.0f;
            float b0_ = 0, b1_ = 0, b2_ = 0, b3_ = 0;
#pragma unroll
            for (int k = 0; k < DD; ++k) {
                float4 ck = *(const float4*)(Acol + k * 20 + q4);
                float rk = Arow[k * 20 + jc];
                b0_ = fmaf(ck.x, rk, b0_);
                b1_ = fmaf(ck.y, rk, b1_);
                b2_ = fmaf(ck.z, rk, b2_);
                b3_ = fmaf(ck.w, rk, b3_);
            }
            float sc = itr * itr;
            a0 = b0_ * sc; a1 = b1_ * sc; a2 = b2_ * sc; a3 = b3_ * sc;
        }

        // column norms + argmax (tie: lower j)
        float cn = a0 * a0;
        cn = fmaf(a1, a1, cn); cn = fmaf(a2, a2, cn); cn = fmaf(a3, a3, cn);
        cn += __shfl_xor(cn, 16, 64);
        cn += __shfl_xor(cn, 32, 64);
        int bj = jc;
#pragma unroll
        for (int off = 32; off >= 1; off >>= 1) {
            float on = __shfl_xor(cn, off, 64);
            int   oj = __shfl_xor(bj, off, 64);
            if (on > cn || (on == cn && oj < bj)) { cn = on; bj = oj; }
        }

        if (jc == bj) {
            vbuf[q4 + 0] = a0; vbuf[q4 + 1] = a1;
            vbuf[q4 + 2] = a2; vbuf[q4 + 3] = a3;
        }
        float vj = vbuf[jc];
        float w0 = a0 * vj, w1 = a1 * vj, w2 = a2 * vj, w3 = a3 * vj;
#pragma unroll
        for (int off = 1; off < 16; off <<= 1) {
            w0 += __shfl_xor(w0, off, 64);
            w1 += __shfl_xor(w1, off, 64);
            w2 += __shfl_xor(w2, off, 64);
            w3 += __shfl_xor(w3, off, 64);
        }
        if (jc == 0) {
            vbuf[q4 + 0] = w0; vbuf[q4 + 1] = w1;
            vbuf[q4 + 2] = w2; vbuf[q4 + 3] = w3;
        }
        vj = vbuf[jc];
        float x0 = a0 * vj, x1 = a1 * vj, x2 = a2 * vj, x3 = a3 * vj;
#pragma unroll
        for (int off = 1; off < 16; off <<= 1) {
            x0 += __shfl_xor(x0, off, 64);
            x1 += __shfl_xor(x1, off, 64);
            x2 += __shfl_xor(x2, off, 64);
            x3 += __shfl_xor(x3, off, 64);
        }
        float nv = x0 * x0;
        nv = fmaf(x1, x1, nv); nv = fmaf(x2, x2, nv); nv = fmaf(x3, x3, nv);
        nv += __shfl_xor(nv, 16, 64);
        nv += __shfl_xor(nv, 32, 64);
        float inv = rsqrtf(fmaxf(nv, 1e-30f));
        if (jc == 0) {
            ubuf[m * 16 + q4 + 0] = x0 * inv;
            ubuf[m * 16 + q4 + 1] = x1 * inv;
            ubuf[m * 16 + q4 + 2] = x2 * inv;
            ubuf[m * 16 + q4 + 3] = x3 * inv;
        }
    }
    float du = ubuf[jc] * ubuf[16 + jc];
#pragma unroll
    for (int off = 1; off < 16; off <<= 1) du += __shfl_xor(du, off, 64);
    if (lane == 0) tsa[qi] = 2.0f - 2.0f * du * du;
}

// ---------------- finalize ----------------
__global__ void finalize_kernel(const float* __restrict__ tsa,
                                const float* __restrict__ part,
                                float* __restrict__ out) {
    __shared__ float red[256];
    int tid = threadIdx.x;
    float s = 0.f;
    for (int i = tid; i < BN; i += 256) s += tsa[i];
    red[tid] = s;
    __syncthreads();
    for (int off = 128; off > 0; off >>= 1) {
        if (tid < off) red[tid] += red[tid + off];
        __syncthreads();
    }
    float tsaSum = red[0];
    __syncthreads();
    red[tid] = part[tid];
    __syncthreads();
    for (int off = 128; off > 0; off >>= 1) {
        if (tid < off) red[tid] += red[tid + off];
        __syncthreads();
    }
    if (tid == 0)
        out[0] = red[0] * (1.0f / (float)(BN * DD)) + 0.1f * (tsaSum * (1.0f / (float)BN));
}

extern "C" void kernel_launch(void* const* d_in, const int* in_sizes, int n_in,
                              void* d_out, int out_size, void* d_ws, size_t ws_size,
                              hipStream_t stream) {
    const float* outputs = (const float*)d_in[0];
    const float* targets = (const float*)d_in[1];
    const float* latent  = (const float*)d_in[2];
    const float* raw     = (const float*)d_in[3];

    char* base = (char*)d_ws;
    float*    tsa   = (float*)base;                                   // BN f32
    float*    part  = (float*)(base + BN * 4);                        // 256 f32
    float*    nrm   = (float*)(base + BN * 4 + 1024);                 // BN f32
    uint4*    rawhl = (uint4*)(base + 2 * BN * 4 + 1024);             // BN*64 B
    unsigned* gcnt2 = (unsigned*)(base + 2 * BN * 4 + 1024 + BN * 64);  // BN*2 u32
    u64*      glist = (u64*)(base + 2 * BN * 4 + 1024 + BN * 64 + BN * 8); // BN*2*CAPH u64

    prep_kernel<<<BN / 256, 256, 0, stream>>>(raw, rawhl, nrm);
    recon_kernel<<<256, 256, 0, stream>>>(outputs, targets, part);
    knnb_kernel<<<2 * (BN / QB), 256, 0, stream>>>(rawhl, nrm, gcnt2, glist);
    sel_eigen_kernel<<<BN / 4, 256, 0, stream>>>(latent, raw, gcnt2, glist, tsa);
    finalize_kernel<<<1, 256, 0, stream>>>(tsa, part, (float*)d_out);
}

// Round 15
// 288.114 us; speedup vs baseline: 1.4281x; 1.1286x over previous
//
#include <hip/hip_runtime.h>

#define BN 16384
#define DD 16
#define KNN 25
#define QB 16
#define CAPH 128
#define NSQ 4

typedef unsigned long long u64;
typedef __attribute__((ext_vector_type(8))) short bf16x8;
typedef __attribute__((ext_vector_type(4))) float f32x4;

__device__ __forceinline__ u64 wave_min_u64(u64 v) {
#pragma unroll
    for (int off = 32; off >= 1; off >>= 1) {
        unsigned lo = (unsigned)v, hi = (unsigned)(v >> 32);
        unsigned olo = __shfl_xor(lo, off, 64);
        unsigned ohi = __shfl_xor(hi, off, 64);
        u64 o = (((u64)ohi) << 32) | olo;
        if (o < v) v = o;
    }
    return v;
}

__device__ __forceinline__ unsigned short f2bf(float f) {
    unsigned u = __float_as_uint(f);
    unsigned r = (u + 0x7FFFu + ((u >> 16) & 1u)) >> 16;   // RNE
    return (unsigned short)r;
}

// ---------------- prep: norms + split-precision bf16 [hi(16)|lo(16)] ----------------
__global__ void prep_kernel(const float* __restrict__ raw, uint4* __restrict__ rawhl,
                            float* __restrict__ nrm) {
    int j = blockIdx.x * 256 + threadIdx.x;
    if (j >= BN) return;
    const float4* rv = (const float4*)raw + j * 4;
    float4 a = rv[0], b = rv[1], c = rv[2], d = rv[3];
    float x[16] = {a.x,a.y,a.z,a.w,b.x,b.y,b.z,b.w,c.x,c.y,c.z,c.w,d.x,d.y,d.z,d.w};
    float s = 0.f;
#pragma unroll
    for (int i = 0; i < 16; ++i) s = fmaf(x[i], x[i], s);
    nrm[j] = s;
    unsigned hp[8], lp[8];
#pragma unroll
    for (int i = 0; i < 8; ++i) {
        unsigned short h0 = f2bf(x[2*i]), h1 = f2bf(x[2*i+1]);
        float f0 = __uint_as_float(((unsigned)h0) << 16);
        float f1 = __uint_as_float(((unsigned)h1) << 16);
        unsigned short l0 = f2bf(x[2*i] - f0), l1 = f2bf(x[2*i+1] - f1);
        hp[i] = (unsigned)h0 | ((unsigned)h1 << 16);
        lp[i] = (unsigned)l0 | ((unsigned)l1 << 16);
    }
    uint4* dst = rawhl + j * 4;
    dst[0] = make_uint4(hp[0], hp[1], hp[2], hp[3]);
    dst[1] = make_uint4(hp[4], hp[5], hp[6], hp[7]);
    dst[2] = make_uint4(lp[0], lp[1], lp[2], lp[3]);
    dst[3] = make_uint4(lp[4], lp[5], lp[6], lp[7]);
}

// ---------------- recon partials ----------------
__global__ void recon_kernel(const float* __restrict__ o, const float* __restrict__ t,
                             float* __restrict__ part) {
    __shared__ float red[256];
    int tid = threadIdx.x;
    int idx = blockIdx.x * 256 + tid;
    float s = 0.f;
    for (int i = idx; i < BN * DD; i += 256 * 256) {
        float d = o[i] - t[i];
        s = fmaf(d, d, s);
    }
    red[tid] = s;
    __syncthreads();
    for (int off = 128; off > 0; off >>= 1) {
        if (tid < off) red[tid] += red[tid + off];
        __syncthreads();
    }
    if (tid == 0) part[blockIdx.x] = red[0];
}

// ------- bounds: one global bound per query from first-4096 sample -------
__global__ __launch_bounds__(256, 8) void bounds_kernel(const uint4* __restrict__ rawhl,
                                                        const float* __restrict__ nrm,
                                                        float* __restrict__ bndp) {
    const int tid  = threadIdx.x;
    const int lane = tid & 63;
    const int w    = tid >> 6;
    const int l15  = lane & 15;
    const int g    = lane >> 4;
    const int row0 = blockIdx.x * QB;

    __shared__ float minbuf[QB][64];   // 4 KB

    const bf16x8* rb = (const bf16x8*)rawhl;
    bf16x8 A1 = rb[(row0 + l15) * 4 + (g & 1)];
    bf16x8 A2 = rb[(row0 + l15) * 4 + 2 + (g & 1)];
    float4 vqn = *(const float4*)(nrm + row0 + g * 4);

    const float INFf = __builtin_inff();
    float mn0 = INFf, mn1 = INFf, mn2 = INFf, mn3 = INFf;
    for (int t = w; t < 256; t += 4) {
        int pt = t * 16 + l15;
        bf16x8 Bf = rb[pt * 4 + g];
        float pn = nrm[pt];
        f32x4 c = {0.f, 0.f, 0.f, 0.f};
        c = __builtin_amdgcn_mfma_f32_16x16x32_bf16(A1, Bf, c, 0, 0, 0);
        c = __builtin_amdgcn_mfma_f32_16x16x32_bf16(A2, Bf, c, 0, 0, 0);
        mn0 = fminf(mn0, fmaxf(fmaf(-2.f, c[0], vqn.x + pn), 0.f));
        mn1 = fminf(mn1, fmaxf(fmaf(-2.f, c[1], vqn.y + pn), 0.f));
        mn2 = fminf(mn2, fmaxf(fmaf(-2.f, c[2], vqn.z + pn), 0.f));
        mn3 = fminf(mn3, fmaxf(fmaf(-2.f, c[3], vqn.w + pn), 0.f));
    }
    minbuf[g * 4 + 0][w * 16 + l15] = mn0;
    minbuf[g * 4 + 1][w * 16 + l15] = mn1;
    minbuf[g * 4 + 2][w * 16 + l15] = mn2;
    minbuf[g * 4 + 3][w * 16 + l15] = mn3;
    __syncthreads();

    // 26 value-extractions: each retires >=1 distinct point's min => bound
    // >= true 26th-smallest over the sample >= global 26th-smallest.
    for (int rr = 0; rr < 4; ++rr) {
        int row = 4 * w + rr;
        float v = minbuf[row][lane];
        float bk = INFf;
        for (int it = 0; it < KNN + 1; ++it) {
            float m = v;
#pragma unroll
            for (int off = 32; off >= 1; off >>= 1)
                m = fminf(m, __shfl_xor(m, off, 64));
            bk = m;
            if (v == m) v = INFf;
        }
        // pre-shifted compare constant: (pn - 2c) <= bk - qn (+ rounding margin)
        if (lane == 0) bndp[row0 + row] = bk - nrm[row0 + row] + 1e-3f;
    }
}

// ------- knnb: 16 rows x half-point-range; pure collect scan, LDS lists -------
__global__ __launch_bounds__(256, 8) void knnb_kernel(const uint4* __restrict__ rawhl,
                                                      const float* __restrict__ nrm,
                                                      const float* __restrict__ bndp,
                                                      unsigned* __restrict__ gcnt2,
                                                      u64* __restrict__ glist) {
    const int tid  = threadIdx.x;
    const int lane = tid & 63;
    const int w    = tid >> 6;
    const int l15  = lane & 15;
    const int g    = lane >> 4;
    const int qg   = blockIdx.x >> 1;
    const int h    = blockIdx.x & 1;
    const int row0 = qg * QB;
    const int pbase = h * (BN / 2);

    __shared__ __align__(16) u64 lists[QB][CAPH];   // 16 KB
    __shared__ int lcnt[QB];

    if (tid < QB) lcnt[tid] = 0;
    __syncthreads();

    const bf16x8* rb = (const bf16x8*)rawhl;
    bf16x8 A1 = rb[(row0 + l15) * 4 + (g & 1)];
    bf16x8 A2 = rb[(row0 + l15) * 4 + 2 + (g & 1)];
    float4 vqn = *(const float4*)(nrm + row0 + g * 4);
    float4 vbp = *(const float4*)(bndp + row0 + g * 4);

    // ---- single pass over this half: 2 VALU/dot test, rare collect ----
    for (int t = w; t < 512; t += 4) {
        int pt = pbase + t * 16 + l15;
        bf16x8 Bf = rb[pt * 4 + g];
        float pn = nrm[pt];
        f32x4 c = {0.f, 0.f, 0.f, 0.f};
        c = __builtin_amdgcn_mfma_f32_16x16x32_bf16(A1, Bf, c, 0, 0, 0);
        c = __builtin_amdgcn_mfma_f32_16x16x32_bf16(A2, Bf, c, 0, 0, 0);
#define COLL(r, QN, BB) { \
        float s = fmaf(-2.f, c[r], pn); \
        if (s <= BB) { \
            float d2 = fmaxf(s + QN, 0.f); \
            int q = g * 4 + r; \
            int pos = atomicAdd(&lcnt[q], 1); \
            if (pos < CAPH) \
                lists[q][pos] = (((u64)__float_as_uint(d2)) << 32) | (unsigned)pt; } }
        COLL(0, vqn.x, vbp.x) COLL(1, vqn.y, vbp.y)
        COLL(2, vqn.z, vbp.z) COLL(3, vqn.w, vbp.w)
#undef COLL
    }
    __syncthreads();

    // ---- flush: coalesced bulk writes, one count store per query-half ----
    for (int rr = 0; rr < 4; ++rr) {
        int qi = 4 * w + rr;
        int cnt = lcnt[qi]; if (cnt > CAPH) cnt = CAPH;
        u64* dst = glist + ((u64)(row0 + qi) * 2 + h) * CAPH;
        for (int e = lane; e < cnt; e += 64) dst[e] = lists[qi][e];
        if (lane == 0) gcnt2[(row0 + qi) * 2 + h] = (unsigned)cnt;
    }
}

// ------------- sel_eigen: 1 row per wave; merge halves, top-25, eigen solve -------------
__global__ __launch_bounds__(256, 7) void sel_eigen_kernel(const float* __restrict__ latent,
                                                           const float* __restrict__ raw,
                                                           const unsigned* __restrict__ gcnt2,
                                                           const u64* __restrict__ glist,
                                                           float* __restrict__ tsa) {
    const int tid  = threadIdx.x;
    const int lane = tid & 63;
    const int w    = tid >> 6;
    const int l15  = lane & 15;
    const int g    = lane >> 4;
    const int qi   = blockIdx.x * 4 + w;

    __shared__ float smem[4 * 1280];   // 20.5 KB, wave-private slices
    float* ews  = smem + w * 1280;
    float* pts  = ews;          // 25 x stride 20
    float* Arow = ews + 512;
    float* Acol = ews + 832;
    float* vbuf = ews + 1152;   // 16
    float* ubuf = ews + 1168;   // 32
    int*   nbrw = (int*)(ews + 1200); // 25

    // ---- selection: merge 2 half-lists, register 26 extract-mins (iter 0 = self) ----
    {
        int c0 = (int)gcnt2[qi * 2 + 0]; if (c0 > CAPH) c0 = CAPH;
        int c1 = (int)gcnt2[qi * 2 + 1]; if (c1 > CAPH) c1 = CAPH;
        const u64* L = glist + (u64)qi * 2 * CAPH;
        u64 k0, k1, k2, k3;
#define GET(dst, i) { int ii = (i); \
        if (ii < c0) dst = L[ii]; \
        else { int jj = ii - c0; dst = (jj < c1) ? L[CAPH + jj] : ~0ull; } }
        GET(k0, lane) GET(k1, lane + 64) GET(k2, lane + 128) GET(k3, lane + 192)
#undef GET
        for (int it = 0; it < KNN + 1; ++it) {
            u64 best = k0;
            if (k1 < best) best = k1;
            if (k2 < best) best = k2;
            if (k3 < best) best = k3;
            best = wave_min_u64(best);
            if (k0 == best) k0 = ~0ull;
            if (k1 == best) k1 = ~0ull;
            if (k2 == best) k2 = ~0ull;
            if (k3 == best) k3 = ~0ull;
            if (lane == 0 && it > 0) nbrw[it - 1] = (int)(best & 0xffffffffu);
        }
    }

    const int q4 = g << 2;
    const int jc = l15;

    for (int m = 0; m < 2; ++m) {
        const float4* src4 = (const float4*)((m == 0) ? latent : raw);
        if (lane < KNN) {
            int nb = nbrw[lane];
            float4 r0 = src4[nb * 4 + 0], r1 = src4[nb * 4 + 1];
            float4 r2 = src4[nb * 4 + 2], r3 = src4[nb * 4 + 3];
            float4* dst = (float4*)(pts + lane * 20);
            dst[0] = r0; dst[1] = r1; dst[2] = r2; dst[3] = r3;
        }
        // gram + mean adjustment: C = G - s s^T / 25
        float g0 = 0, g1 = 0, g2 = 0, g3 = 0;
        float s0 = 0, s1 = 0, s2 = 0, s3 = 0, sj = 0;
        for (int k = 0; k < KNN; ++k) {
            float4 qv = *(const float4*)(pts + k * 20 + q4);
            float rj = pts[k * 20 + jc];
            g0 = fmaf(qv.x, rj, g0); g1 = fmaf(qv.y, rj, g1);
            g2 = fmaf(qv.z, rj, g2); g3 = fmaf(qv.w, rj, g3);
            s0 += qv.x; s1 += qv.y; s2 += qv.z; s3 += qv.w; sj += rj;
        }
        const float i25 = 1.0f / 25.0f;
        float sjs = sj * i25;
        float a0 = fmaf(-s0, sjs, g0);
        float a1 = fmaf(-s1, sjs, g1);
        float a2 = fmaf(-s2, sjs, g2);
        float a3 = fmaf(-s3, sjs, g3);

        for (int sq = 0; sq < NSQ; ++sq) {
            Arow[(q4 + 0) * 20 + jc] = a0;
            Arow[(q4 + 1) * 20 + jc] = a1;
            Arow[(q4 + 2) * 20 + jc] = a2;
            Arow[(q4 + 3) * 20 + jc] = a3;
            *(float4*)(Acol + jc * 20 + q4) = make_float4(a0, a1, a2, a3);
            float t = 0.f;
            if (jc == q4 + 0) t += a0;
            if (jc == q4 + 1) t += a1;
            if (jc == q4 + 2) t += a2;
            if (jc == q4 + 3) t += a3;
#pragma unroll
            for (int off = 32; off >= 1; off >>= 1) t += __shfl_xor(t, off, 64);
            float itr = (t > 0.f) ? (1.0f / t) : 1.0f;
            float b0_ = 0, b1_ = 0, b2_ = 0, b3_ = 0;
#pragma unroll
            for (int k = 0; k < DD; ++k) {
                float4 ck = *(const float4*)(Acol + k * 20 + q4);
                float rk = Arow[k * 20 + jc];
                b0_ = fmaf(ck.x, rk, b0_);
                b1_ = fmaf(ck.y, rk, b1_);
                b2_ = fmaf(ck.z, rk, b2_);
                b3_ = fmaf(ck.w, rk, b3_);
            }
            float sc = itr * itr;
            a0 = b0_ * sc; a1 = b1_ * sc; a2 = b2_ * sc; a3 = b3_ * sc;
        }

        // column norms + argmax (tie: lower j)
        float cn = a0 * a0;
        cn = fmaf(a1, a1, cn); cn = fmaf(a2, a2, cn); cn = fmaf(a3, a3, cn);
        cn += __shfl_xor(cn, 16, 64);
        cn += __shfl_xor(cn, 32, 64);
        int bj = jc;
#pragma unroll
        for (int off = 32; off >= 1; off >>= 1) {
            float on = __shfl_xor(cn, off, 64);
            int   oj = __shfl_xor(bj, off, 64);
            if (on > cn || (on == cn && oj < bj)) { cn = on; bj = oj; }
        }

        if (jc == bj) {
            vbuf[q4 + 0] = a0; vbuf[q4 + 1] = a1;
            vbuf[q4 + 2] = a2; vbuf[q4 + 3] = a3;
        }
        float vj = vbuf[jc];
        float w0 = a0 * vj, w1 = a1 * vj, w2 = a2 * vj, w3 = a3 * vj;
#pragma unroll
        for (int off = 1; off < 16; off <<= 1) {
            w0 += __shfl_xor(w0, off, 64);
            w1 += __shfl_xor(w1, off, 64);
            w2 += __shfl_xor(w2, off, 64);
            w3 += __shfl_xor(w3, off, 64);
        }
        if (jc == 0) {
            vbuf[q4 + 0] = w0; vbuf[q4 + 1] = w1;
            vbuf[q4 + 2] = w2; vbuf[q4 + 3] = w3;
        }
        vj = vbuf[jc];
        float x0 = a0 * vj, x1 = a1 * vj, x2 = a2 * vj, x3 = a3 * vj;
#pragma unroll
        for (int off = 1; off < 16; off <<= 1) {
            x0 += __shfl_xor(x0, off, 64);
            x1 += __shfl_xor(x1, off, 64);
            x2 += __shfl_xor(x2, off, 64);
            x3 += __shfl_xor(x3, off, 64);
        }
        float nv = x0 * x0;
        nv = fmaf(x1, x1, nv); nv = fmaf(x2, x2, nv); nv = fmaf(x3, x3, nv);
        nv += __shfl_xor(nv, 16, 64);
        nv += __shfl_xor(nv, 32, 64);
        float inv = rsqrtf(fmaxf(nv, 1e-30f));
        if (jc == 0) {
            ubuf[m * 16 + q4 + 0] = x0 * inv;
            ubuf[m * 16 + q4 + 1] = x1 * inv;
            ubuf[m * 16 + q4 + 2] = x2 * inv;
            ubuf[m * 16 + q4 + 3] = x3 * inv;
        }
    }
    float du = ubuf[jc] * ubuf[16 + jc];
#pragma unroll
    for (int off = 1; off < 16; off <<= 1) du += __shfl_xor(du, off, 64);
    if (lane == 0) tsa[qi] = 2.0f - 2.0f * du * du;
}

// ---------------- finalize ----------------
__global__ void finalize_kernel(const float* __restrict__ tsa,
                                const float* __restrict__ part,
                                float* __restrict__ out) {
    __shared__ float red[256];
    int tid = threadIdx.x;
    float s = 0.f;
    for (int i = tid; i < BN; i += 256) s += tsa[i];
    red[tid] = s;
    __syncthreads();
    for (int off = 128; off > 0; off >>= 1) {
        if (tid < off) red[tid] += red[tid + off];
        __syncthreads();
    }
    float tsaSum = red[0];
    __syncthreads();
    red[tid] = part[tid];
    __syncthreads();
    for (int off = 128; off > 0; off >>= 1) {
        if (tid < off) red[tid] += red[tid + off];
        __syncthreads();
    }
    if (tid == 0)
        out[0] = red[0] * (1.0f / (float)(BN * DD)) + 0.1f * (tsaSum * (1.0f / (float)BN));
}

extern "C" void kernel_launch(void* const* d_in, const int* in_sizes, int n_in,
                              void* d_out, int out_size, void* d_ws, size_t ws_size,
                              hipStream_t stream) {
    const float* outputs = (const float*)d_in[0];
    const float* targets = (const float*)d_in[1];
    const float* latent  = (const float*)d_in[2];
    const float* raw     = (const float*)d_in[3];

    char* base = (char*)d_ws;
    float*    tsa   = (float*)base;                                   // BN f32
    float*    part  = (float*)(base + BN * 4);                        // 256 f32
    float*    nrm   = (float*)(base + BN * 4 + 1024);                 // BN f32
    float*    bndp  = (float*)(base + 2 * BN * 4 + 1024);             // BN f32
    uint4*    rawhl = (uint4*)(base + 3 * BN * 4 + 1024);             // BN*64 B
    unsigned* gcnt2 = (unsigned*)(base + 3 * BN * 4 + 1024 + BN * 64);  // BN*2 u32
    u64*      glist = (u64*)(base + 3 * BN * 4 + 1024 + BN * 64 + BN * 8); // BN*2*CAPH u64

    prep_kernel<<<BN / 256, 256, 0, stream>>>(raw, rawhl, nrm);
    recon_kernel<<<256, 256, 0, stream>>>(outputs, targets, part);
    bounds_kernel<<<BN / QB, 256, 0, stream>>>(rawhl, nrm, bndp);
    knnb_kernel<<<2 * (BN / QB), 256, 0, stream>>>(rawhl, nrm, bndp, gcnt2, glist);
    sel_eigen_kernel<<<BN / 4, 256, 0, stream>>>(latent, raw, gcnt2, glist, tsa);
    finalize_kernel<<<1, 256, 0, stream>>>(tsa, part, (float*)d_out);
}

// Round 16
// 285.920 us; speedup vs baseline: 1.4390x; 1.0077x over previous
//
#include <hip/hip_runtime.h>

#define BN 16384
#define DD 16
#define KNN 25
#define QB 16
#define CAPH 128
#define NSQ 4

typedef unsigned long long u64;
typedef __attribute__((ext_vector_type(8))) short bf16x8;
typedef __attribute__((ext_vector_type(4))) float f32x4;

__device__ __forceinline__ u64 wave_min_u64(u64 v) {
#pragma unroll
    for (int off = 32; off >= 1; off >>= 1) {
        unsigned lo = (unsigned)v, hi = (unsigned)(v >> 32);
        unsigned olo = __shfl_xor(lo, off, 64);
        unsigned ohi = __shfl_xor(hi, off, 64);
        u64 o = (((u64)ohi) << 32) | olo;
        if (o < v) v = o;
    }
    return v;
}

__device__ __forceinline__ unsigned short f2bf(float f) {
    unsigned u = __float_as_uint(f);
    unsigned r = (u + 0x7FFFu + ((u >> 16) & 1u)) >> 16;   // RNE
    return (unsigned short)r;
}

// ---------------- prep: norms + split-precision bf16 [hi(16)|lo(16)] ----------------
__global__ void prep_kernel(const float* __restrict__ raw, uint4* __restrict__ rawhl,
                            float* __restrict__ nrm) {
    int j = blockIdx.x * 256 + threadIdx.x;
    if (j >= BN) return;
    const float4* rv = (const float4*)raw + j * 4;
    float4 a = rv[0], b = rv[1], c = rv[2], d = rv[3];
    float x[16] = {a.x,a.y,a.z,a.w,b.x,b.y,b.z,b.w,c.x,c.y,c.z,c.w,d.x,d.y,d.z,d.w};
    float s = 0.f;
#pragma unroll
    for (int i = 0; i < 16; ++i) s = fmaf(x[i], x[i], s);
    nrm[j] = s;
    unsigned hp[8], lp[8];
#pragma unroll
    for (int i = 0; i < 8; ++i) {
        unsigned short h0 = f2bf(x[2*i]), h1 = f2bf(x[2*i+1]);
        float f0 = __uint_as_float(((unsigned)h0) << 16);
        float f1 = __uint_as_float(((unsigned)h1) << 16);
        unsigned short l0 = f2bf(x[2*i] - f0), l1 = f2bf(x[2*i+1] - f1);
        hp[i] = (unsigned)h0 | ((unsigned)h1 << 16);
        lp[i] = (unsigned)l0 | ((unsigned)l1 << 16);
    }
    uint4* dst = rawhl + j * 4;
    dst[0] = make_uint4(hp[0], hp[1], hp[2], hp[3]);
    dst[1] = make_uint4(hp[4], hp[5], hp[6], hp[7]);
    dst[2] = make_uint4(lp[0], lp[1], lp[2], lp[3]);
    dst[3] = make_uint4(lp[4], lp[5], lp[6], lp[7]);
}

// ---------------- recon partials ----------------
__global__ void recon_kernel(const float* __restrict__ o, const float* __restrict__ t,
                             float* __restrict__ part) {
    __shared__ float red[256];
    int tid = threadIdx.x;
    int idx = blockIdx.x * 256 + tid;
    float s = 0.f;
    for (int i = idx; i < BN * DD; i += 256 * 256) {
        float d = o[i] - t[i];
        s = fmaf(d, d, s);
    }
    red[tid] = s;
    __syncthreads();
    for (int off = 128; off > 0; off >>= 1) {
        if (tid < off) red[tid] += red[tid + off];
        __syncthreads();
    }
    if (tid == 0) part[blockIdx.x] = red[0];
}

// ------- bounds: one global bound per query from first-4096 sample -------
__global__ __launch_bounds__(256, 8) void bounds_kernel(const uint4* __restrict__ rawhl,
                                                        const float* __restrict__ nrm,
                                                        float* __restrict__ bndp) {
    const int tid  = threadIdx.x;
    const int lane = tid & 63;
    const int w    = tid >> 6;
    const int l15  = lane & 15;
    const int g    = lane >> 4;
    const int row0 = blockIdx.x * QB;

    __shared__ float minbuf[QB][64];   // 4 KB

    const bf16x8* rb = (const bf16x8*)rawhl;
    bf16x8 A1 = rb[(row0 + l15) * 4 + (g & 1)];
    bf16x8 A2 = rb[(row0 + l15) * 4 + 2 + (g & 1)];
    float4 vqn = *(const float4*)(nrm + row0 + g * 4);

    const float INFf = __builtin_inff();
    float mn0 = INFf, mn1 = INFf, mn2 = INFf, mn3 = INFf;
    for (int t = w; t < 256; t += 4) {
        int pt = t * 16 + l15;
        bf16x8 Bf = rb[pt * 4 + g];
        float pn = nrm[pt];
        f32x4 c = {0.f, 0.f, 0.f, 0.f};
        c = __builtin_amdgcn_mfma_f32_16x16x32_bf16(A1, Bf, c, 0, 0, 0);
        c = __builtin_amdgcn_mfma_f32_16x16x32_bf16(A2, Bf, c, 0, 0, 0);
        mn0 = fminf(mn0, fmaxf(fmaf(-2.f, c[0], vqn.x + pn), 0.f));
        mn1 = fminf(mn1, fmaxf(fmaf(-2.f, c[1], vqn.y + pn), 0.f));
        mn2 = fminf(mn2, fmaxf(fmaf(-2.f, c[2], vqn.z + pn), 0.f));
        mn3 = fminf(mn3, fmaxf(fmaf(-2.f, c[3], vqn.w + pn), 0.f));
    }
    minbuf[g * 4 + 0][w * 16 + l15] = mn0;
    minbuf[g * 4 + 1][w * 16 + l15] = mn1;
    minbuf[g * 4 + 2][w * 16 + l15] = mn2;
    minbuf[g * 4 + 3][w * 16 + l15] = mn3;
    __syncthreads();

    // 26 value-extractions: each retires >=1 distinct point's min => bound
    // >= true 26th-smallest over the sample >= global 26th-smallest.
    for (int rr = 0; rr < 4; ++rr) {
        int row = 4 * w + rr;
        float v = minbuf[row][lane];
        float bk = INFf;
        for (int it = 0; it < KNN + 1; ++it) {
            float m = v;
#pragma unroll
            for (int off = 32; off >= 1; off >>= 1)
                m = fminf(m, __shfl_xor(m, off, 64));
            bk = m;
            if (v == m) v = INFf;
        }
        // pre-shifted compare constant: (pn - 2c) <= bk - qn (+ rounding margin)
        if (lane == 0) bndp[row0 + row] = bk - nrm[row0 + row] + 1e-3f;
    }
}

// ------- knnb: 16 rows x half-point-range; pure collect scan, LDS lists -------
__global__ __launch_bounds__(256, 8) void knnb_kernel(const uint4* __restrict__ rawhl,
                                                      const float* __restrict__ nrm,
                                                      const float* __restrict__ bndp,
                                                      unsigned* __restrict__ gcnt2,
                                                      u64* __restrict__ glist) {
    const int tid  = threadIdx.x;
    const int lane = tid & 63;
    const int w    = tid >> 6;
    const int l15  = lane & 15;
    const int g    = lane >> 4;
    const int qg   = blockIdx.x >> 1;
    const int h    = blockIdx.x & 1;
    const int row0 = qg * QB;
    const int pbase = h * (BN / 2);

    __shared__ __align__(16) u64 lists[QB][CAPH];   // 16 KB
    __shared__ int lcnt[QB];

    if (tid < QB) lcnt[tid] = 0;
    __syncthreads();

    const bf16x8* rb = (const bf16x8*)rawhl;
    bf16x8 A1 = rb[(row0 + l15) * 4 + (g & 1)];
    bf16x8 A2 = rb[(row0 + l15) * 4 + 2 + (g & 1)];
    float4 vqn = *(const float4*)(nrm + row0 + g * 4);
    float4 vbp = *(const float4*)(bndp + row0 + g * 4);

    // ---- single pass over this half: 2 VALU/dot test, rare collect ----
    for (int t = w; t < 512; t += 4) {
        int pt = pbase + t * 16 + l15;
        bf16x8 Bf = rb[pt * 4 + g];
        float pn = nrm[pt];
        f32x4 c = {0.f, 0.f, 0.f, 0.f};
        c = __builtin_amdgcn_mfma_f32_16x16x32_bf16(A1, Bf, c, 0, 0, 0);
        c = __builtin_amdgcn_mfma_f32_16x16x32_bf16(A2, Bf, c, 0, 0, 0);
#define COLL(r, QN, BB) { \
        float s = fmaf(-2.f, c[r], pn); \
        if (s <= BB) { \
            float d2 = fmaxf(s + QN, 0.f); \
            int q = g * 4 + r; \
            int pos = atomicAdd(&lcnt[q], 1); \
            if (pos < CAPH) \
                lists[q][pos] = (((u64)__float_as_uint(d2)) << 32) | (unsigned)pt; } }
        COLL(0, vqn.x, vbp.x) COLL(1, vqn.y, vbp.y)
        COLL(2, vqn.z, vbp.z) COLL(3, vqn.w, vbp.w)
#undef COLL
    }
    __syncthreads();

    // ---- flush: coalesced bulk writes, one count store per query-half ----
    for (int rr = 0; rr < 4; ++rr) {
        int qi = 4 * w + rr;
        int cnt = lcnt[qi]; if (cnt > CAPH) cnt = CAPH;
        u64* dst = glist + ((u64)(row0 + qi) * 2 + h) * CAPH;
        for (int e = lane; e < cnt; e += 64) dst[e] = lists[qi][e];
        if (lane == 0) gcnt2[(row0 + qi) * 2 + h] = (unsigned)cnt;
    }
}

// ------------- sel_eigen: 1 row per wave; merge halves, top-25, eigen solve -------------
__global__ __launch_bounds__(256, 4) void sel_eigen_kernel(const float* __restrict__ latent,
                                                           const float* __restrict__ raw,
                                                           const unsigned* __restrict__ gcnt2,
                                                           const u64* __restrict__ glist,
                                                           float* __restrict__ tsa) {
    const int tid  = threadIdx.x;
    const int lane = tid & 63;
    const int w    = tid >> 6;
    const int l15  = lane & 15;
    const int g    = lane >> 4;
    const int qi   = blockIdx.x * 4 + w;

    __shared__ float smem[4 * 1280];   // 20.5 KB, wave-private slices
    float* ews  = smem + w * 1280;
    float* pts  = ews;          // 25 x stride 20
    float* Arow = ews + 512;
    float* Acol = ews + 832;
    float* vbuf = ews + 1152;   // 16
    float* ubuf = ews + 1168;   // 32
    int*   nbrw = (int*)(ews + 1200); // 25

    // ---- selection: merge 2 half-lists, register 26 extract-mins (iter 0 = self) ----
    {
        int c0 = (int)gcnt2[qi * 2 + 0]; if (c0 > CAPH) c0 = CAPH;
        int c1 = (int)gcnt2[qi * 2 + 1]; if (c1 > CAPH) c1 = CAPH;
        const u64* L = glist + (u64)qi * 2 * CAPH;
        u64 k0, k1, k2, k3;
#define GET(dst, i) { int ii = (i); \
        if (ii < c0) dst = L[ii]; \
        else { int jj = ii - c0; dst = (jj < c1) ? L[CAPH + jj] : ~0ull; } }
        GET(k0, lane) GET(k1, lane + 64) GET(k2, lane + 128) GET(k3, lane + 192)
#undef GET
        for (int it = 0; it < KNN + 1; ++it) {
            u64 best = k0;
            if (k1 < best) best = k1;
            if (k2 < best) best = k2;
            if (k3 < best) best = k3;
            best = wave_min_u64(best);
            if (k0 == best) k0 = ~0ull;
            if (k1 == best) k1 = ~0ull;
            if (k2 == best) k2 = ~0ull;
            if (k3 == best) k3 = ~0ull;
            if (lane == 0 && it > 0) nbrw[it - 1] = (int)(best & 0xffffffffu);
        }
    }

    const int q4 = g << 2;
    const int jc = l15;

    for (int m = 0; m < 2; ++m) {
        const float4* src4 = (const float4*)((m == 0) ? latent : raw);
        if (lane < KNN) {
            int nb = nbrw[lane];
            float4 r0 = src4[nb * 4 + 0], r1 = src4[nb * 4 + 1];
            float4 r2 = src4[nb * 4 + 2], r3 = src4[nb * 4 + 3];
            float4* dst = (float4*)(pts + lane * 20);
            dst[0] = r0; dst[1] = r1; dst[2] = r2; dst[3] = r3;
        }
        // gram + mean adjustment: C = G - s s^T / 25
        float g0 = 0, g1 = 0, g2 = 0, g3 = 0;
        float s0 = 0, s1 = 0, s2 = 0, s3 = 0, sj = 0;
        for (int k = 0; k < KNN; ++k) {
            float4 qv = *(const float4*)(pts + k * 20 + q4);
            float rj = pts[k * 20 + jc];
            g0 = fmaf(qv.x, rj, g0); g1 = fmaf(qv.y, rj, g1);
            g2 = fmaf(qv.z, rj, g2); g3 = fmaf(qv.w, rj, g3);
            s0 += qv.x; s1 += qv.y; s2 += qv.z; s3 += qv.w; sj += rj;
        }
        const float i25 = 1.0f / 25.0f;
        float sjs = sj * i25;
        float a0 = fmaf(-s0, sjs, g0);
        float a1 = fmaf(-s1, sjs, g1);
        float a2 = fmaf(-s2, sjs, g2);
        float a3 = fmaf(-s3, sjs, g3);

        for (int sq = 0; sq < NSQ; ++sq) {
            Arow[(q4 + 0) * 20 + jc] = a0;
            Arow[(q4 + 1) * 20 + jc] = a1;
            Arow[(q4 + 2) * 20 + jc] = a2;
            Arow[(q4 + 3) * 20 + jc] = a3;
            *(float4*)(Acol + jc * 20 + q4) = make_float4(a0, a1, a2, a3);
            float t = 0.f;
            if (jc == q4 + 0) t += a0;
            if (jc == q4 + 1) t += a1;
            if (jc == q4 + 2) t += a2;
            if (jc == q4 + 3) t += a3;
#pragma unroll
            for (int off = 32; off >= 1; off >>= 1) t += __shfl_xor(t, off, 64);
            float itr = (t > 0.f) ? (1.0f / t) : 1.0f;
            float b0_ = 0, b1_ = 0, b2_ = 0, b3_ = 0;
#pragma unroll
            for (int k = 0; k < DD; ++k) {
                float4 ck = *(const float4*)(Acol + k * 20 + q4);
                float rk = Arow[k * 20 + jc];
                b0_ = fmaf(ck.x, rk, b0_);
                b1_ = fmaf(ck.y, rk, b1_);
                b2_ = fmaf(ck.z, rk, b2_);
                b3_ = fmaf(ck.w, rk, b3_);
            }
            float sc = itr * itr;
            a0 = b0_ * sc; a1 = b1_ * sc; a2 = b2_ * sc; a3 = b3_ * sc;
        }

        // column norms + argmax (tie: lower j)
        float cn = a0 * a0;
        cn = fmaf(a1, a1, cn); cn = fmaf(a2, a2, cn); cn = fmaf(a3, a3, cn);
        cn += __shfl_xor(cn, 16, 64);
        cn += __shfl_xor(cn, 32, 64);
        int bj = jc;
#pragma unroll
        for (int off = 32; off >= 1; off >>= 1) {
            float on = __shfl_xor(cn, off, 64);
            int   oj = __shfl_xor(bj, off, 64);
            if (on > cn || (on == cn && oj < bj)) { cn = on; bj = oj; }
        }

        if (jc == bj) {
            vbuf[q4 + 0] = a0; vbuf[q4 + 1] = a1;
            vbuf[q4 + 2] = a2; vbuf[q4 + 3] = a3;
        }
        float vj = vbuf[jc];
        float w0 = a0 * vj, w1 = a1 * vj, w2 = a2 * vj, w3 = a3 * vj;
#pragma unroll
        for (int off = 1; off < 16; off <<= 1) {
            w0 += __shfl_xor(w0, off, 64);
            w1 += __shfl_xor(w1, off, 64);
            w2 += __shfl_xor(w2, off, 64);
            w3 += __shfl_xor(w3, off, 64);
        }
        if (jc == 0) {
            vbuf[q4 + 0] = w0; vbuf[q4 + 1] = w1;
            vbuf[q4 + 2] = w2; vbuf[q4 + 3] = w3;
        }
        vj = vbuf[jc];
        float x0 = a0 * vj, x1 = a1 * vj, x2 = a2 * vj, x3 = a3 * vj;
#pragma unroll
        for (int off = 1; off < 16; off <<= 1) {
            x0 += __shfl_xor(x0, off, 64);
            x1 += __shfl_xor(x1, off, 64);
            x2 += __shfl_xor(x2, off, 64);
            x3 += __shfl_xor(x3, off, 64);
        }
        float nv = x0 * x0;
        nv = fmaf(x1, x1, nv); nv = fmaf(x2, x2, nv); nv = fmaf(x3, x3, nv);
        nv += __shfl_xor(nv, 16, 64);
        nv += __shfl_xor(nv, 32, 64);
        float inv = rsqrtf(fmaxf(nv, 1e-30f));
        if (jc == 0) {
            ubuf[m * 16 + q4 + 0] = x0 * inv;
            ubuf[m * 16 + q4 + 1] = x1 * inv;
            ubuf[m * 16 + q4 + 2] = x2 * inv;
            ubuf[m * 16 + q4 + 3] = x3 * inv;
        }
    }
    float du = ubuf[jc] * ubuf[16 + jc];
#pragma unroll
    for (int off = 1; off < 16; off <<= 1) du += __shfl_xor(du, off, 64);
    if (lane == 0) tsa[qi] = 2.0f - 2.0f * du * du;
}

// ---------------- finalize ----------------
__global__ void finalize_kernel(const float* __restrict__ tsa,
                                const float* __restrict__ part,
                                float* __restrict__ out) {
    __shared__ float red[256];
    int tid = threadIdx.x;
    float s = 0.f;
    for (int i = tid; i < BN; i += 256) s += tsa[i];
    red[tid] = s;
    __syncthreads();
    for (int off = 128; off > 0; off >>= 1) {
        if (tid < off) red[tid] += red[tid + off];
        __syncthreads();
    }
    float tsaSum = red[0];
    __syncthreads();
    red[tid] = part[tid];
    __syncthreads();
    for (int off = 128; off > 0; off >>= 1) {
        if (tid < off) red[tid] += red[tid + off];
        __syncthreads();
    }
    if (tid == 0)
        out[0] = red[0] * (1.0f / (float)(BN * DD)) + 0.1f * (tsaSum * (1.0f / (float)BN));
}

extern "C" void kernel_launch(void* const* d_in, const int* in_sizes, int n_in,
                              void* d_out, int out_size, void* d_ws, size_t ws_size,
                              hipStream_t stream) {
    const float* outputs = (const float*)d_in[0];
    const float* targets = (const float*)d_in[1];
    const float* latent  = (const float*)d_in[2];
    const float* raw     = (const float*)d_in[3];

    char* base = (char*)d_ws;
    float*    tsa   = (float*)base;                                   // BN f32
    float*    part  = (float*)(base + BN * 4);                        // 256 f32
    float*    nrm   = (float*)(base + BN * 4 + 1024);                 // BN f32
    float*    bndp  = (float*)(base + 2 * BN * 4 + 1024);             // BN f32
    uint4*    rawhl = (uint4*)(base + 3 * BN * 4 + 1024);             // BN*64 B
    unsigned* gcnt2 = (unsigned*)(base + 3 * BN * 4 + 1024 + BN * 64);  // BN*2 u32
    u64*      glist = (u64*)(base + 3 * BN * 4 + 1024 + BN * 64 + BN * 8); // BN*2*CAPH u64

    prep_kernel<<<BN / 256, 256, 0, stream>>>(raw, rawhl, nrm);
    recon_kernel<<<256, 256, 0, stream>>>(outputs, targets, part);
    bounds_kernel<<<BN / QB, 256, 0, stream>>>(rawhl, nrm, bndp);
    knnb_kernel<<<2 * (BN / QB), 256, 0, stream>>>(rawhl, nrm, bndp, gcnt2, glist);
    sel_eigen_kernel<<<BN / 4, 256, 0, stream>>>(latent, raw, gcnt2, glist, tsa);
    finalize_kernel<<<1, 256, 0, stream>>>(tsa, part, (float*)d_out);
}

// Round 17
// 266.966 us; speedup vs baseline: 1.5412x; 1.0710x over previous
//
#include <hip/hip_runtime.h>

#define BN 16384
#define DD 16
#define KNN 25
#define QB 16
#define CAPH 128
#define NSQ 4

typedef unsigned long long u64;
typedef __attribute__((ext_vector_type(8))) short bf16x8;
typedef __attribute__((ext_vector_type(4))) float f32x4;

__device__ __forceinline__ u64 wave_min_u64(u64 v) {
#pragma unroll
    for (int off = 32; off >= 1; off >>= 1) {
        unsigned lo = (unsigned)v, hi = (unsigned)(v >> 32);
        unsigned olo = __shfl_xor(lo, off, 64);
        unsigned ohi = __shfl_xor(hi, off, 64);
        u64 o = (((u64)ohi) << 32) | olo;
        if (o < v) v = o;
    }
    return v;
}

__device__ __forceinline__ unsigned short f2bf(float f) {
    unsigned u = __float_as_uint(f);
    unsigned r = (u + 0x7FFFu + ((u >> 16) & 1u)) >> 16;   // RNE
    return (unsigned short)r;
}

// ---------------- prep: norms + split-precision bf16 [hi(16)|lo(16)] ----------------
__global__ void prep_kernel(const float* __restrict__ raw, uint4* __restrict__ rawhl,
                            float* __restrict__ nrm) {
    int j = blockIdx.x * 256 + threadIdx.x;
    if (j >= BN) return;
    const float4* rv = (const float4*)raw + j * 4;
    float4 a = rv[0], b = rv[1], c = rv[2], d = rv[3];
    float x[16] = {a.x,a.y,a.z,a.w,b.x,b.y,b.z,b.w,c.x,c.y,c.z,c.w,d.x,d.y,d.z,d.w};
    float s = 0.f;
#pragma unroll
    for (int i = 0; i < 16; ++i) s = fmaf(x[i], x[i], s);
    nrm[j] = s;
    unsigned hp[8], lp[8];
#pragma unroll
    for (int i = 0; i < 8; ++i) {
        unsigned short h0 = f2bf(x[2*i]), h1 = f2bf(x[2*i+1]);
        float f0 = __uint_as_float(((unsigned)h0) << 16);
        float f1 = __uint_as_float(((unsigned)h1) << 16);
        unsigned short l0 = f2bf(x[2*i] - f0), l1 = f2bf(x[2*i+1] - f1);
        hp[i] = (unsigned)h0 | ((unsigned)h1 << 16);
        lp[i] = (unsigned)l0 | ((unsigned)l1 << 16);
    }
    uint4* dst = rawhl + j * 4;
    dst[0] = make_uint4(hp[0], hp[1], hp[2], hp[3]);
    dst[1] = make_uint4(hp[4], hp[5], hp[6], hp[7]);
    dst[2] = make_uint4(lp[0], lp[1], lp[2], lp[3]);
    dst[3] = make_uint4(lp[4], lp[5], lp[6], lp[7]);
}

// ---------------- recon partials ----------------
__global__ void recon_kernel(const float* __restrict__ o, const float* __restrict__ t,
                             float* __restrict__ part) {
    __shared__ float red[256];
    int tid = threadIdx.x;
    int idx = blockIdx.x * 256 + tid;
    float s = 0.f;
    for (int i = idx; i < BN * DD; i += 256 * 256) {
        float d = o[i] - t[i];
        s = fmaf(d, d, s);
    }
    red[tid] = s;
    __syncthreads();
    for (int off = 128; off > 0; off >>= 1) {
        if (tid < off) red[tid] += red[tid + off];
        __syncthreads();
    }
    if (tid == 0) part[blockIdx.x] = red[0];
}

// ------- bounds: one global bound per query from first-4096 sample -------
__global__ __launch_bounds__(256, 8) void bounds_kernel(const uint4* __restrict__ rawhl,
                                                        const float* __restrict__ nrm,
                                                        float* __restrict__ bndp) {
    const int tid  = threadIdx.x;
    const int lane = tid & 63;
    const int w    = tid >> 6;
    const int l15  = lane & 15;
    const int g    = lane >> 4;
    const int row0 = blockIdx.x * QB;

    __shared__ float minbuf[QB][64];   // 4 KB

    const bf16x8* rb = (const bf16x8*)rawhl;
    bf16x8 A1 = rb[(row0 + l15) * 4 + (g & 1)];
    bf16x8 A2 = rb[(row0 + l15) * 4 + 2 + (g & 1)];
    float4 vqn = *(const float4*)(nrm + row0 + g * 4);

    const float INFf = __builtin_inff();
    float mn0 = INFf, mn1 = INFf, mn2 = INFf, mn3 = INFf;
    for (int t = w; t < 256; t += 4) {
        int pt = t * 16 + l15;
        bf16x8 Bf = rb[pt * 4 + g];
        float pn = nrm[pt];
        f32x4 c = {0.f, 0.f, 0.f, 0.f};
        c = __builtin_amdgcn_mfma_f32_16x16x32_bf16(A1, Bf, c, 0, 0, 0);
        c = __builtin_amdgcn_mfma_f32_16x16x32_bf16(A2, Bf, c, 0, 0, 0);
        mn0 = fminf(mn0, fmaxf(fmaf(-2.f, c[0], vqn.x + pn), 0.f));
        mn1 = fminf(mn1, fmaxf(fmaf(-2.f, c[1], vqn.y + pn), 0.f));
        mn2 = fminf(mn2, fmaxf(fmaf(-2.f, c[2], vqn.z + pn), 0.f));
        mn3 = fminf(mn3, fmaxf(fmaf(-2.f, c[3], vqn.w + pn), 0.f));
    }
    minbuf[g * 4 + 0][w * 16 + l15] = mn0;
    minbuf[g * 4 + 1][w * 16 + l15] = mn1;
    minbuf[g * 4 + 2][w * 16 + l15] = mn2;
    minbuf[g * 4 + 3][w * 16 + l15] = mn3;
    __syncthreads();

    // 26 value-extractions: each retires >=1 distinct point's min => bound
    // >= true 26th-smallest over the sample >= global 26th-smallest.
    for (int rr = 0; rr < 4; ++rr) {
        int row = 4 * w + rr;
        float v = minbuf[row][lane];
        float bk = INFf;
        for (int it = 0; it < KNN + 1; ++it) {
            float m = v;
#pragma unroll
            for (int off = 32; off >= 1; off >>= 1)
                m = fminf(m, __shfl_xor(m, off, 64));
            bk = m;
            if (v == m) v = INFf;
        }
        // pre-shifted compare constant: (pn - 2c) <= bk - qn (+ rounding margin)
        if (lane == 0) bndp[row0 + row] = bk - nrm[row0 + row] + 1e-3f;
    }
}

// ------- knnb: 16 rows x half-point-range; pure collect scan, LDS lists -------
__global__ __launch_bounds__(256, 8) void knnb_kernel(const uint4* __restrict__ rawhl,
                                                      const float* __restrict__ nrm,
                                                      const float* __restrict__ bndp,
                                                      unsigned* __restrict__ gcnt2,
                                                      u64* __restrict__ glist) {
    const int tid  = threadIdx.x;
    const int lane = tid & 63;
    const int w    = tid >> 6;
    const int l15  = lane & 15;
    const int g    = lane >> 4;
    const int qg   = blockIdx.x >> 1;
    const int h    = blockIdx.x & 1;
    const int row0 = qg * QB;
    const int pbase = h * (BN / 2);

    __shared__ __align__(16) u64 lists[QB][CAPH];   // 16 KB
    __shared__ int lcnt[QB];

    if (tid < QB) lcnt[tid] = 0;
    __syncthreads();

    const bf16x8* rb = (const bf16x8*)rawhl;
    bf16x8 A1 = rb[(row0 + l15) * 4 + (g & 1)];
    bf16x8 A2 = rb[(row0 + l15) * 4 + 2 + (g & 1)];
    float4 vqn = *(const float4*)(nrm + row0 + g * 4);
    float4 vbp = *(const float4*)(bndp + row0 + g * 4);

    // ---- single pass over this half: 2 VALU/dot test, rare collect ----
    for (int t = w; t < 512; t += 4) {
        int pt = pbase + t * 16 + l15;
        bf16x8 Bf = rb[pt * 4 + g];
        float pn = nrm[pt];
        f32x4 c = {0.f, 0.f, 0.f, 0.f};
        c = __builtin_amdgcn_mfma_f32_16x16x32_bf16(A1, Bf, c, 0, 0, 0);
        c = __builtin_amdgcn_mfma_f32_16x16x32_bf16(A2, Bf, c, 0, 0, 0);
#define COLL(r, QN, BB) { \
        float s = fmaf(-2.f, c[r], pn); \
        if (s <= BB) { \
            float d2 = fmaxf(s + QN, 0.f); \
            int q = g * 4 + r; \
            int pos = atomicAdd(&lcnt[q], 1); \
            if (pos < CAPH) \
                lists[q][pos] = (((u64)__float_as_uint(d2)) << 32) | (unsigned)pt; } }
        COLL(0, vqn.x, vbp.x) COLL(1, vqn.y, vbp.y)
        COLL(2, vqn.z, vbp.z) COLL(3, vqn.w, vbp.w)
#undef COLL
    }
    __syncthreads();

    // ---- flush: coalesced bulk writes, one count store per query-half ----
    for (int rr = 0; rr < 4; ++rr) {
        int qi = 4 * w + rr;
        int cnt = lcnt[qi]; if (cnt > CAPH) cnt = CAPH;
        u64* dst = glist + ((u64)(row0 + qi) * 2 + h) * CAPH;
        for (int e = lane; e < cnt; e += 64) dst[e] = lists[qi][e];
        if (lane == 0) gcnt2[(row0 + qi) * 2 + h] = (unsigned)cnt;
    }
}

// ------------- sel_eigen: 1 row per wave; top-25 select, MFMA eigen solve -------------
__global__ __launch_bounds__(256, 4) void sel_eigen_kernel(const float* __restrict__ latent,
                                                           const float* __restrict__ raw,
                                                           const unsigned* __restrict__ gcnt2,
                                                           const u64* __restrict__ glist,
                                                           float* __restrict__ tsa) {
    const int lane = threadIdx.x & 63;
    const int w    = threadIdx.x >> 6;
    const int l15  = lane & 15;
    const int g    = lane >> 4;
    const int qi   = blockIdx.x * 4 + w;

    __shared__ __align__(16) float smem[4 * 1360];   // 21.8 KB, wave-private slices
    float* ews  = smem + w * 1360;
    float* pts  = ews;            // 32 rows x stride 20 (rows 25-31 zero pad)
    float* Arow = ews + 640;      // 16 x 20: A[r][c] at r*20+c
    float* Acol = ews + 960;      // 16 x 20: A[r][c] at c*20+r
    float* vbuf = ews + 1280;     // 16
    float* ubuf = ews + 1296;     // 32
    int*   nbrw = (int*)(ews + 1328); // 25

    // ---- selection: merge 2 half-lists, register 26 extract-mins (iter 0 = self) ----
    {
        int c0 = (int)gcnt2[qi * 2 + 0]; if (c0 > CAPH) c0 = CAPH;
        int c1 = (int)gcnt2[qi * 2 + 1]; if (c1 > CAPH) c1 = CAPH;
        const u64* L = glist + (u64)qi * 2 * CAPH;
        u64 k0, k1, k2, k3;
#define GET(dst, i) { int ii = (i); \
        if (ii < c0) dst = L[ii]; \
        else { int jj = ii - c0; dst = (jj < c1) ? L[CAPH + jj] : ~0ull; } }
        GET(k0, lane) GET(k1, lane + 64) GET(k2, lane + 128) GET(k3, lane + 192)
#undef GET
        for (int it = 0; it < KNN + 1; ++it) {
            u64 best = k0;
            if (k1 < best) best = k1;
            if (k2 < best) best = k2;
            if (k3 < best) best = k3;
            best = wave_min_u64(best);
            if (k0 == best) k0 = ~0ull;
            if (k1 == best) k1 = ~0ull;
            if (k2 == best) k2 = ~0ull;
            if (k3 == best) k3 = ~0ull;
            if (lane == 0 && it > 0) nbrw[it - 1] = (int)(best & 0xffffffffu);
        }
    }

    const int q4 = g << 2;
    const int jc = l15;
    const int c8 = 8 * (g & 1);
    const float i25 = 1.0f / 25.0f;

    // zero pad rows 25..31 of pts (cols 0..15)
    if (lane >= 25 && lane < 32) {
        float4 z = make_float4(0.f, 0.f, 0.f, 0.f);
        float4* dst = (float4*)(pts + lane * 20);
        dst[0] = z; dst[1] = z; dst[2] = z; dst[3] = z;
    }

    // ones A-fragment for column-sum MFMA: A[0][k]=1, rows 1..15 = 0
    bf16x8 Fones;
#pragma unroll
    for (int i = 0; i < 8; ++i) Fones[i] = (l15 == 0) ? (short)0x3F80 : (short)0;

    for (int m = 0; m < 2; ++m) {
        const float4* src4 = (const float4*)((m == 0) ? latent : raw);
        if (lane < KNN) {
            int nb = nbrw[lane];
            float4 r0 = src4[nb * 4 + 0], r1 = src4[nb * 4 + 1];
            float4 r2 = src4[nb * 4 + 2], r3 = src4[nb * 4 + 3];
            float4* dst = (float4*)(pts + lane * 20);
            dst[0] = r0; dst[1] = r1; dst[2] = r2; dst[3] = r3;
        }

        // ---- P fragments: F = P[8g+i][l15] (serves as A=P^T and B=P) ----
        bf16x8 Fh, Fl;
#pragma unroll
        for (int i = 0; i < 8; ++i) {
            float pv = pts[(8 * g + i) * 20 + l15];
            unsigned short hh = f2bf(pv);
            float hf = __uint_as_float(((unsigned)hh) << 16);
            unsigned short ll = f2bf(pv - hf);
            Fh[i] = (short)hh;
            Fl[i] = (short)ll;
        }

        // ---- gram G = P^T P (4 MFMAs, full hi/lo cross terms) ----
        f32x4 gacc = {0.f, 0.f, 0.f, 0.f};
        gacc = __builtin_amdgcn_mfma_f32_16x16x32_bf16(Fh, Fh, gacc, 0, 0, 0);
        gacc = __builtin_amdgcn_mfma_f32_16x16x32_bf16(Fh, Fl, gacc, 0, 0, 0);
        gacc = __builtin_amdgcn_mfma_f32_16x16x32_bf16(Fl, Fh, gacc, 0, 0, 0);
        gacc = __builtin_amdgcn_mfma_f32_16x16x32_bf16(Fl, Fl, gacc, 0, 0, 0);

        // ---- column sums s = 1^T P via ones-row MFMA ----
        f32x4 sacc = {0.f, 0.f, 0.f, 0.f};
        sacc = __builtin_amdgcn_mfma_f32_16x16x32_bf16(Fones, Fh, sacc, 0, 0, 0);
        sacc = __builtin_amdgcn_mfma_f32_16x16x32_bf16(Fones, Fl, sacc, 0, 0, 0);
        if (g == 0) vbuf[jc] = sacc[0];

        // ---- C = G - s s^T / 25 ----
        float s_jc = vbuf[jc] * i25;
        float4 s4 = *(const float4*)(vbuf + q4);
        float a0 = fmaf(-s4.x, s_jc, gacc[0]);
        float a1 = fmaf(-s4.y, s_jc, gacc[1]);
        float a2 = fmaf(-s4.z, s_jc, gacc[2]);
        float a3 = fmaf(-s4.w, s_jc, gacc[3]);

        // ---- NSQ trace-normalized squarings via split-bf16 MFMA ----
        for (int sq = 0; sq < NSQ; ++sq) {
            Arow[(q4 + 0) * 20 + jc] = a0;
            Arow[(q4 + 1) * 20 + jc] = a1;
            Arow[(q4 + 2) * 20 + jc] = a2;
            Arow[(q4 + 3) * 20 + jc] = a3;
            *(float4*)(Acol + jc * 20 + q4) = make_float4(a0, a1, a2, a3);
            float t = 0.f;
            if (jc == q4 + 0) t += a0;
            if (jc == q4 + 1) t += a1;
            if (jc == q4 + 2) t += a2;
            if (jc == q4 + 3) t += a3;
#pragma unroll
            for (int off = 32; off >= 1; off >>= 1) t += __shfl_xor(t, off, 64);
            float itr = (t > 0.f) ? (1.0f / t) : 1.0f;

            // A-frags: row l15 of A, cols c8..c8+7 -> hi and lo
            float4 ar0 = *(const float4*)(Arow + l15 * 20 + c8);
            float4 ar1 = *(const float4*)(Arow + l15 * 20 + c8 + 4);
            float av[8] = {ar0.x, ar0.y, ar0.z, ar0.w, ar1.x, ar1.y, ar1.z, ar1.w};
            bf16x8 AFh, AFl;
#pragma unroll
            for (int i = 0; i < 8; ++i) {
                unsigned short hh = f2bf(av[i]);
                float hf = __uint_as_float(((unsigned)hh) << 16);
                unsigned short ll = f2bf(av[i] - hf);
                AFh[i] = (short)hh;
                AFl[i] = (short)ll;
            }
            // B-frag: rows c8..c8+7 of A, col l15; hi for g<2, lo for g>=2
            float4 bc0 = *(const float4*)(Acol + l15 * 20 + c8);
            float4 bc1 = *(const float4*)(Acol + l15 * 20 + c8 + 4);
            float bv[8] = {bc0.x, bc0.y, bc0.z, bc0.w, bc1.x, bc1.y, bc1.z, bc1.w};
            bf16x8 BF;
#pragma unroll
            for (int i = 0; i < 8; ++i) {
                unsigned short hh = f2bf(bv[i]);
                if (g < 2) BF[i] = (short)hh;
                else {
                    float hf = __uint_as_float(((unsigned)hh) << 16);
                    BF[i] = (short)f2bf(bv[i] - hf);
                }
            }
            f32x4 acc = {0.f, 0.f, 0.f, 0.f};
            acc = __builtin_amdgcn_mfma_f32_16x16x32_bf16(AFh, BF, acc, 0, 0, 0);
            acc = __builtin_amdgcn_mfma_f32_16x16x32_bf16(AFl, BF, acc, 0, 0, 0);
            float sc = itr * itr;
            a0 = acc[0] * sc; a1 = acc[1] * sc; a2 = acc[2] * sc; a3 = acc[3] * sc;
        }

        // ---- column norms + argmax (tie: lower j) ----
        float cn = a0 * a0;
        cn = fmaf(a1, a1, cn); cn = fmaf(a2, a2, cn); cn = fmaf(a3, a3, cn);
        cn += __shfl_xor(cn, 16, 64);
        cn += __shfl_xor(cn, 32, 64);
        int bj = jc;
#pragma unroll
        for (int off = 32; off >= 1; off >>= 1) {
            float on = __shfl_xor(cn, off, 64);
            int   oj = __shfl_xor(bj, off, 64);
            if (on > cn || (on == cn && oj < bj)) { cn = on; bj = oj; }
        }

        if (jc == bj) {
            vbuf[q4 + 0] = a0; vbuf[q4 + 1] = a1;
            vbuf[q4 + 2] = a2; vbuf[q4 + 3] = a3;
        }
        float vj = vbuf[jc];
        float w0 = a0 * vj, w1 = a1 * vj, w2 = a2 * vj, w3 = a3 * vj;
#pragma unroll
        for (int off = 1; off < 16; off <<= 1) {
            w0 += __shfl_xor(w0, off, 64);
            w1 += __shfl_xor(w1, off, 64);
            w2 += __shfl_xor(w2, off, 64);
            w3 += __shfl_xor(w3, off, 64);
        }
        if (jc == 0) {
            vbuf[q4 + 0] = w0; vbuf[q4 + 1] = w1;
            vbuf[q4 + 2] = w2; vbuf[q4 + 3] = w3;
        }
        vj = vbuf[jc];
        float x0 = a0 * vj, x1 = a1 * vj, x2 = a2 * vj, x3 = a3 * vj;
#pragma unroll
        for (int off = 1; off < 16; off <<= 1) {
            x0 += __shfl_xor(x0, off, 64);
            x1 += __shfl_xor(x1, off, 64);
            x2 += __shfl_xor(x2, off, 64);
            x3 += __shfl_xor(x3, off, 64);
        }
        float nv = x0 * x0;
        nv = fmaf(x1, x1, nv); nv = fmaf(x2, x2, nv); nv = fmaf(x3, x3, nv);
        nv += __shfl_xor(nv, 16, 64);
        nv += __shfl_xor(nv, 32, 64);
        float inv = rsqrtf(fmaxf(nv, 1e-30f));
        if (jc == 0) {
            ubuf[m * 16 + q4 + 0] = x0 * inv;
            ubuf[m * 16 + q4 + 1] = x1 * inv;
            ubuf[m * 16 + q4 + 2] = x2 * inv;
            ubuf[m * 16 + q4 + 3] = x3 * inv;
        }
    }
    float du = ubuf[jc] * ubuf[16 + jc];
#pragma unroll
    for (int off = 1; off < 16; off <<= 1) du += __shfl_xor(du, off, 64);
    if (lane == 0) tsa[qi] = 2.0f - 2.0f * du * du;
}

// ---------------- finalize ----------------
__global__ void finalize_kernel(const float* __restrict__ tsa,
                                const float* __restrict__ part,
                                float* __restrict__ out) {
    __shared__ float red[256];
    int tid = threadIdx.x;
    float s = 0.f;
    for (int i = tid; i < BN; i += 256) s += tsa[i];
    red[tid] = s;
    __syncthreads();
    for (int off = 128; off > 0; off >>= 1) {
        if (tid < off) red[tid] += red[tid + off];
        __syncthreads();
    }
    float tsaSum = red[0];
    __syncthreads();
    red[tid] = part[tid];
    __syncthreads();
    for (int off = 128; off > 0; off >>= 1) {
        if (tid < off) red[tid] += red[tid + off];
        __syncthreads();
    }
    if (tid == 0)
        out[0] = red[0] * (1.0f / (float)(BN * DD)) + 0.1f * (tsaSum * (1.0f / (float)BN));
}

extern "C" void kernel_launch(void* const* d_in, const int* in_sizes, int n_in,
                              void* d_out, int out_size, void* d_ws, size_t ws_size,
                              hipStream_t stream) {
    const float* outputs = (const float*)d_in[0];
    const float* targets = (const float*)d_in[1];
    const float* latent  = (const float*)d_in[2];
    const float* raw     = (const float*)d_in[3];

    char* base = (char*)d_ws;
    float*    tsa   = (float*)base;                                   // BN f32
    float*    part  = (float*)(base + BN * 4);                        // 256 f32
    float*    nrm   = (float*)(base + BN * 4 + 1024);                 // BN f32
    float*    bndp  = (float*)(base + 2 * BN * 4 + 1024);             // BN f32
    uint4*    rawhl = (uint4*)(base + 3 * BN * 4 + 1024);             // BN*64 B
    unsigned* gcnt2 = (unsigned*)(base + 3 * BN * 4 + 1024 + BN * 64);  // BN*2 u32
    u64*      glist = (u64*)(base + 3 * BN * 4 + 1024 + BN * 64 + BN * 8); // BN*2*CAPH u64

    prep_kernel<<<BN / 256, 256, 0, stream>>>(raw, rawhl, nrm);
    recon_kernel<<<256, 256, 0, stream>>>(outputs, targets, part);
    bounds_kernel<<<BN / QB, 256, 0, stream>>>(rawhl, nrm, bndp);
    knnb_kernel<<<2 * (BN / QB), 256, 0, stream>>>(rawhl, nrm, bndp, gcnt2, glist);
    sel_eigen_kernel<<<BN / 4, 256, 0, stream>>>(latent, raw, gcnt2, glist, tsa);
    finalize_kernel<<<1, 256, 0, stream>>>(tsa, part, (float*)d_out);
}